// Round 9
// baseline (611.352 us; speedup 1.0000x reference)
//
#include <hip/hip_runtime.h>

#define ACT_SHIFT (-4.5951198501345898f)   // log(1/(1-0.01) - 1)
#define DELTA 0.5f
#define XS 25600                            // 160*160
#define YS 160
#define NVOX 4096000

typedef __attribute__((ext_vector_type(8))) short short8;
typedef __attribute__((ext_vector_type(4))) float f32x4;
typedef __attribute__((ext_vector_type(2))) unsigned int u32x2;
typedef __attribute__((ext_vector_type(4))) unsigned int u32x4;

__device__ __forceinline__ float softplusf(float x) {
    return x > 20.f ? x : log1pf(expf(x));
}
__device__ __forceinline__ unsigned short f2b(float x) {        // RNE (prep paths)
    unsigned int u = __float_as_uint(x);
    u += 0x7fffu + ((u >> 16) & 1u);
    return (unsigned short)(u >> 16);
}
__device__ __forceinline__ unsigned short f2b_fast(float x) {   // round-half-up (verified r6)
    return (unsigned short)((__float_as_uint(x) + 0x8000u) >> 16);
}
__device__ __forceinline__ float blo(unsigned int u) { return __uint_as_float(u << 16); }
__device__ __forceinline__ float bhi(unsigned int u) { return __uint_as_float(u & 0xffff0000u); }

__device__ __forceinline__ void trisetup(float px, float py, float pz,
                                         int& ix, int& iy, int& iz,
                                         float& fx, float& fy, float& fz) {
    float sx = (px + 1.f) * 0.5f * 159.f;
    float sy = (py + 1.f) * 0.5f * 159.f;
    float sz = (pz + 1.f) * 0.5f * 159.f;
    sx = fminf(fmaxf(sx, 0.f), 159.f);
    sy = fminf(fmaxf(sy, 0.f), 159.f);
    sz = fminf(fmaxf(sz, 0.f), 159.f);
    ix = (int)sx; if (ix > 158) ix = 158;
    iy = (int)sy; if (iy > 158) iy = 158;
    iz = (int)sz; if (iz > 158) iz = 158;
    fx = sx - (float)ix;
    fy = sy - (float)iy;
    fz = sz - (float)iz;
}

// ================= grid builders =================
// VOX64: entry(x,y,z) = {ch0..11(z) bf16, ch0..11(z+1) bf16, d(z) f32, d(z+1) f32, pad}
__global__ void k_t64(const float* __restrict__ k0, const float* __restrict__ dg,
                      unsigned int* __restrict__ grid) {
    int tid = blockIdx.x * 256 + threadIdx.x;
    if (tid >= NVOX) return;
    int z = tid % 160;
    int t1 = (z < 159) ? tid + 1 : tid;
    unsigned int w[16];
    #pragma unroll
    for (int j = 0; j < 6; j++) {
        w[j]   = (unsigned int)f2b(k0[(size_t)(2*j)*NVOX + tid]) | ((unsigned int)f2b(k0[(size_t)(2*j+1)*NVOX + tid]) << 16);
        w[6+j] = (unsigned int)f2b(k0[(size_t)(2*j)*NVOX + t1])  | ((unsigned int)f2b(k0[(size_t)(2*j+1)*NVOX + t1])  << 16);
    }
    w[12] = __float_as_uint(dg[tid]);
    w[13] = __float_as_uint(dg[t1]);
    w[14] = 0u; w[15] = 0u;
    u32x4* dst = (u32x4*)(grid + (size_t)tid * 16);
    dst[0] = *(u32x4*)(w);  dst[1] = *(u32x4*)(w+4);
    dst[2] = *(u32x4*)(w+8); dst[3] = *(u32x4*)(w+12);
}

__global__ void k_t32(const float* __restrict__ k0, const float* __restrict__ dg,
                      unsigned int* __restrict__ grid) {
    int tid = blockIdx.x * 256 + threadIdx.x;
    if (tid >= NVOX) return;
    unsigned int w[8];
    #pragma unroll
    for (int j = 0; j < 6; j++)
        w[j] = (unsigned int)f2b(k0[(size_t)(2*j)*NVOX + tid]) | ((unsigned int)f2b(k0[(size_t)(2*j+1)*NVOX + tid]) << 16);
    w[6] = __float_as_uint(dg[tid]);
    w[7] = 0u;
    u32x4* dst = (u32x4*)(grid + (size_t)tid * 8);
    dst[0] = *(u32x4*)(w); dst[1] = *(u32x4*)(w+4);
}
__global__ void k_t24(const float* __restrict__ k0, unsigned int* __restrict__ grid) {
    int tid = blockIdx.x * 256 + threadIdx.x;
    if (tid >= NVOX) return;
    unsigned int o[6];
    #pragma unroll
    for (int j = 0; j < 6; j++)
        o[j] = (unsigned int)f2b(k0[(size_t)(2*j)*NVOX + tid]) | ((unsigned int)f2b(k0[(size_t)(2*j+1)*NVOX + tid]) << 16);
    unsigned int* dst = grid + (size_t)tid * 6;
    #pragma unroll
    for (int j = 0; j < 6; j++) dst[j] = o[j];
}

// ================= small prep kernels =================
// Feature order: slots 0..26 = vd_emb, 27 = pad0, 28..36 = k0 ch3..11, 37..63 = 0
__global__ void k_wprep(const float* __restrict__ W0, const float* __restrict__ W1,
                        const float* __restrict__ W2,
                        unsigned short* __restrict__ Wt0, unsigned short* __restrict__ Wt1,
                        unsigned short* __restrict__ Wt2) {
    int id = blockIdx.x * 256 + threadIdx.x;
    if (id < 128 * 64) {
        int n = id >> 6, k = id & 63;
        float v = 0.f;
        if (k < 27)                 v = W0[(9 + k) * 128 + n];
        else if (k >= 28 && k < 37) v = W0[(k - 28) * 128 + n];
        Wt0[id] = f2b(v);
    }
    if (id < 128 * 128) { int n = id >> 7, k = id & 127; Wt1[id] = f2b(W1[k*128 + n]); }
    if (id < 16 * 128)  { int n = id >> 7, k = id & 127; Wt2[id] = (n < 3) ? f2b(W2[k*3 + n]) : 0; }
}

__global__ void k_starts(const int* __restrict__ rid, int* __restrict__ starts, int M, int R) {
    int r = blockIdx.x * blockDim.x + threadIdx.x;
    if (r > R) return;
    int lo = 0, hi = M;
    while (lo < hi) { int mid = (lo + hi) >> 1; if (rid[mid] < r) lo = mid + 1; else hi = mid; }
    starts[r] = lo;
}

__global__ void k_vdemb(const float* __restrict__ vd, unsigned short* __restrict__ emb, int R) {
    int r = blockIdx.x * blockDim.x + threadIdx.x;
    if (r >= R) return;
    float e[28];
    float v0 = vd[3*r], v1 = vd[3*r+1], v2 = vd[3*r+2];
    e[0] = v0; e[1] = v1; e[2] = v2;
    float v[3] = {v0, v1, v2};
    #pragma unroll
    for (int d = 0; d < 3; d++) {
        #pragma unroll
        for (int p = 0; p < 4; p++) {
            float a = v[d] * (float)(1 << p);
            e[3 + d*4 + p]  = sinf(a);
            e[15 + d*4 + p] = cosf(a);
        }
    }
    e[27] = 0.f;
    unsigned short* o = emb + r * 28;
    #pragma unroll
    for (int j = 0; j < 28; j++) o[j] = f2b(e[j]);
}

__global__ void k_densityC(const float* __restrict__ dg, const float* __restrict__ xyz,
                           float2* __restrict__ alog, int M) {
    int i = blockIdx.x * blockDim.x + threadIdx.x;
    if (i >= M) return;
    int ix, iy, iz; float fx, fy, fz;
    trisetup(xyz[3*i], xyz[3*i+1], xyz[3*i+2], ix, iy, iz, fx, fy, fz);
    const float* g = dg + ix * XS + iy * YS + iz;
    float gx = 1.f - fx, gy = 1.f - fy, gz = 1.f - fz;
    float v =
        gx * (gy * (gz * g[0]      + fz * g[1])      + fy * (gz * g[YS]      + fz * g[YS+1])) +
        fx * (gy * (gz * g[XS]     + fz * g[XS+1])   + fy * (gz * g[XS+YS]   + fz * g[XS+YS+1]));
    float sp = softplusf(v + ACT_SHIFT);
    float l  = -sp * DELTA;
    alog[i] = make_float2(1.f - expf(l), fmaxf(l, -15.9424285f));
}

// ================= gather: 2 threads/point =================
// rec[i] (32B): w0=(c3,c4) w1=(c5,c6) w2=(c7,c8) w3=(c9,c10) w4=(c11,0) w5..7=diff f32
template<int VOX>
__global__ __launch_bounds__(256) void k_gather(
    const unsigned int* __restrict__ grid, const float* __restrict__ dg,
    const float* __restrict__ xyz,
    u32x4* __restrict__ rec, float2* __restrict__ alog, int M) {

    const int t = blockIdx.x * 256 + threadIdx.x;
    const int p = t >> 1;
    const int dx = t & 1;
    if (p >= M) return;
    const int i = p;

    int ix, iy, iz; float fx, fy, fz;
    trisetup(xyz[3*i], xyz[3*i+1], xyz[3*i+2], ix, iy, iz, fx, fy, fz);
    float gz = 1.f - fz;
    float wx = dx ? fx : (1.f - fx);
    float wy[2] = {wx * (1.f - fy), wx * fy};

    float ch[12];
    #pragma unroll
    for (int c = 0; c < 12; c++) ch[c] = 0.f;
    float dd = 0.f;
    const int x = ix + dx;

    #pragma unroll
    for (int dy = 0; dy < 2; dy++) {
        float wc = wy[dy];
        size_t idx = (size_t)(x * 160 + (iy + dy)) * 160 + iz;
        if (VOX == 64) {
            const u32x4* e = (const u32x4*)(grid + idx * 16);
            u32x4 q0 = e[0], q1 = e[1], q2 = e[2], q3 = e[3];
            unsigned int wz[6]  = {q0[0],q0[1],q0[2],q0[3],q1[0],q1[1]};
            unsigned int wz1[6] = {q1[2],q1[3],q2[0],q2[1],q2[2],q2[3]};
            #pragma unroll
            for (int j = 0; j < 6; j++) {
                ch[2*j]   += wc * (gz * blo(wz[j]) + fz * blo(wz1[j]));
                ch[2*j+1] += wc * (gz * bhi(wz[j]) + fz * bhi(wz1[j]));
            }
            dd += wc * (gz * __uint_as_float(q3[0]) + fz * __uint_as_float(q3[1]));
        } else if (VOX == 32) {
            const u32x4* e0 = (const u32x4*)(grid + idx * 8);
            const u32x4* e1 = (const u32x4*)(grid + (idx + 1) * 8);
            u32x4 a0 = e0[0], a1 = e0[1], b0 = e1[0], b1 = e1[1];
            unsigned int wz[6]  = {a0[0],a0[1],a0[2],a0[3],a1[0],a1[1]};
            unsigned int wz1[6] = {b0[0],b0[1],b0[2],b0[3],b1[0],b1[1]};
            #pragma unroll
            for (int j = 0; j < 6; j++) {
                ch[2*j]   += wc * (gz * blo(wz[j]) + fz * blo(wz1[j]));
                ch[2*j+1] += wc * (gz * bhi(wz[j]) + fz * bhi(wz1[j]));
            }
            dd += wc * (gz * __uint_as_float(a1[2]) + fz * __uint_as_float(b1[2]));
        } else {
            const u32x2* e = (const u32x2*)(grid + idx * 6);
            u32x2 a0 = e[0], a1 = e[1], a2 = e[2], a3 = e[3], a4 = e[4], a5 = e[5];
            unsigned int wz[6]  = {a0[0],a0[1],a1[0],a1[1],a2[0],a2[1]};
            unsigned int wz1[6] = {a3[0],a3[1],a4[0],a4[1],a5[0],a5[1]};
            #pragma unroll
            for (int j = 0; j < 6; j++) {
                ch[2*j]   += wc * (gz * blo(wz[j]) + fz * blo(wz1[j]));
                ch[2*j+1] += wc * (gz * bhi(wz[j]) + fz * bhi(wz1[j]));
            }
            const float* dr = dg + (size_t)(x * 160 + (iy + dy)) * 160 + iz;
            dd += wc * (gz * dr[0] + fz * dr[1]);
        }
    }

    #pragma unroll
    for (int c = 0; c < 12; c++) ch[c] += __shfl_xor(ch[c], 1);
    dd += __shfl_xor(dd, 1);

    if (dx == 0) {
        unsigned int w[8];
        w[0] = (unsigned int)f2b(ch[3]) | ((unsigned int)f2b(ch[4]) << 16);
        w[1] = (unsigned int)f2b(ch[5]) | ((unsigned int)f2b(ch[6]) << 16);
        w[2] = (unsigned int)f2b(ch[7]) | ((unsigned int)f2b(ch[8]) << 16);
        w[3] = (unsigned int)f2b(ch[9]) | ((unsigned int)f2b(ch[10]) << 16);
        w[4] = (unsigned int)f2b(ch[11]);
        w[5] = __float_as_uint(ch[0]);
        w[6] = __float_as_uint(ch[1]);
        w[7] = __float_as_uint(ch[2]);
        rec[(size_t)i*2]     = *(u32x4*)(w);
        rec[(size_t)i*2 + 1] = *(u32x4*)(w + 4);
    } else {
        float sp = softplusf(dd + ACT_SHIFT);
        float l  = -sp * DELTA;
        alog[i] = make_float2(1.f - expf(l), fmaxf(l, -15.9424285f));
    }
}

// ================= wave-per-ray scan =================
__global__ void k_scanw(const float2* __restrict__ alog, const int* __restrict__ starts,
                        float* __restrict__ wts, float* __restrict__ out, int R) {
    const int r = (blockIdx.x * blockDim.x + threadIdx.x) >> 6;
    const int lane = threadIdx.x & 63;
    if (r >= R) return;
    const int s = starts[r], e = starts[r + 1];
    float carry = 0.f;
    for (int i0 = s; i0 < e; i0 += 64) {
        int idx = i0 + lane;
        bool pr = idx < e;
        float a = 0.f, x = 0.f;
        if (pr) { float2 v = alog[idx]; a = v.x; x = v.y; }
        float incl = x;
        #pragma unroll
        for (int d = 1; d < 64; d <<= 1) {
            float tv = __shfl_up(incl, d);
            if (lane >= d) incl += tv;
        }
        if (pr) wts[idx] = a * expf(carry + (incl - x));
        carry += __shfl(incl, 63);
    }
    float ainv = expf(carry);
    if (lane == 0) { out[3*r] = ainv; out[3*r+1] = ainv; out[3*r+2] = ainv; }
}

// ================= MFMA MLP v4: round-6 verified addressing + merged LDS (4 blocks/CU) ===
// feat staged into hL bytes [0,16KB) row-major 128B/row (XOR swz); L1 accumulates in regs,
// then h1 overwrites the whole 32KB buffer (round-6 row-major 256B/row, XOR swz).
__global__ __launch_bounds__(256, 4) void k_mlp_s(
    const u32x4* __restrict__ rec, const int* __restrict__ rid,
    const unsigned short* __restrict__ vemb, const float* __restrict__ wts,
    const unsigned short* __restrict__ Wt0, const float* __restrict__ b0,
    const unsigned short* __restrict__ Wt1, const float* __restrict__ b1,
    const unsigned short* __restrict__ Wt2, const float* __restrict__ b2,
    float* __restrict__ out, int M) {

    __shared__ char hL[128 * 256];     // 32 KB; feat aliased into first 16 KB
    __shared__ float diffL[128 * 3];
    __shared__ float wgtL[128];
    __shared__ int   ridL[128];

    const int t = threadIdx.x;
    const int base = blockIdx.x * 128;

    // ---- staging: feat rows into hL[0..16KB) (row-major, swizzled) ----
    if (t < 128) {
        const int i = base + t;
        unsigned int fr[32];
        #pragma unroll
        for (int j = 19; j < 32; j++) fr[j] = 0u;
        float wpt = 0.f; int r = 0;
        float d0 = 0.f, d1 = 0.f, d2 = 0.f;
        if (i < M) {
            u32x4 r0 = rec[(size_t)i*2];
            u32x4 r1 = rec[(size_t)i*2 + 1];
            r = rid[i];
            wpt = wts[i];
            const unsigned int* vp = (const unsigned int*)(vemb + (size_t)r * 28);
            #pragma unroll
            for (int j = 0; j < 14; j++) fr[j] = vp[j];   // vemb (slot 27 pad=0)
            fr[14] = r0[0]; fr[15] = r0[1]; fr[16] = r0[2]; fr[17] = r0[3];
            fr[18] = r1[0] & 0xffffu;                      // (c11, 0)
            d0 = __uint_as_float(r1[1]); d1 = __uint_as_float(r1[2]); d2 = __uint_as_float(r1[3]);
        } else {
            #pragma unroll
            for (int j = 0; j < 19; j++) fr[j] = 0u;
        }
        diffL[t*3 + 0] = d0; diffL[t*3 + 1] = d1; diffL[t*3 + 2] = d2;
        wgtL[t] = wpt;
        ridL[t] = r;
        char* fp = hL + t * 128;
        unsigned int rs = (unsigned int)((t & 7) << 4);
        #pragma unroll
        for (int j = 0; j < 8; j++)
            *(u32x4*)(fp + ((16u*j) ^ rs)) = *(u32x4*)(fr + 4*j);
    }

    const int lane = t & 63;
    const int w = t >> 6;
    const int g = lane >> 4;
    const int ln = lane & 15;

    // ---- hoist B1 ----
    short8 B1[2][2];
    float bias0[2];
    #pragma unroll
    for (int ntl = 0; ntl < 2; ntl++) {
        const int n0 = (2*w + ntl) * 16;
        const char* wb0 = (const char*)Wt0 + (n0 + ln) * 128 + 16*g;
        B1[ntl][0] = *(const short8*)(wb0);
        B1[ntl][1] = *(const short8*)(wb0 + 64);
        bias0[ntl] = b0[n0 + ln];
    }
    __syncthreads();   // feat staged

    // ---- layer 1: all 8 m-tiles, wave's 2 n-tiles; accumulate in regs ----
    f32x4 acc1[8][2];
    #pragma unroll
    for (int mt = 0; mt < 8; mt++) {
        const int arow = mt*16 + ln;
        const unsigned int aswz = (unsigned int)((arow & 7) << 4);
        const char* ab = hL + arow * 128;
        short8 a0 = *(const short8*)(ab + ((16u*g)        ^ aswz));
        short8 a1 = *(const short8*)(ab + ((64u + 16u*g)  ^ aswz));
        #pragma unroll
        for (int ntl = 0; ntl < 2; ntl++) {
            f32x4 acc = {bias0[ntl], bias0[ntl], bias0[ntl], bias0[ntl]};
            acc = __builtin_amdgcn_mfma_f32_16x16x32_bf16(a0, B1[ntl][0], acc, 0, 0, 0);
            acc = __builtin_amdgcn_mfma_f32_16x16x32_bf16(a1, B1[ntl][1], acc, 0, 0, 0);
            acc1[mt][ntl] = acc;
        }
    }
    __syncthreads();   // all feat reads done -> safe to overwrite with h1

    // ---- store h1 (round-6 addressing), then hoist B2 in the barrier shadow ----
    #pragma unroll
    for (int mt = 0; mt < 8; mt++) {
        #pragma unroll
        for (int ntl = 0; ntl < 2; ntl++) {
            const int n0 = (2*w + ntl) * 16;
            #pragma unroll
            for (int v = 0; v < 4; v++) {
                int row = mt*16 + 4*g + v;
                unsigned short hv = f2b_fast(fmaxf(acc1[mt][ntl][v], 0.f));
                *(unsigned short*)(hL + (((unsigned)(row*256 + (n0+ln)*2)) ^ ((unsigned)((row & 7) << 4)))) = hv;
            }
        }
    }
    short8 B2[2][4];
    float bias1[2];
    #pragma unroll
    for (int ntl = 0; ntl < 2; ntl++) {
        const int n0 = (2*w + ntl) * 16;
        const char* wb1 = (const char*)Wt1 + (n0 + ln) * 256 + 16*g;
        #pragma unroll
        for (int kk = 0; kk < 4; kk++)
            B2[ntl][kk] = *(const short8*)(wb1 + 64*kk);
        bias1[ntl] = b1[n0 + ln];
    }
    __syncthreads();   // h1 visible

    // ---- layer 2: reads of all h1 rows -> acc in regs; stores deferred past barrier ----
    f32x4 acc2[8][2];
    #pragma unroll
    for (int mt = 0; mt < 8; mt++) {
        const int arow = mt*16 + ln;
        const unsigned int aswz = (unsigned int)((arow & 7) << 4);
        const char* ab = hL + arow * 256;
        short8 a0 = *(const short8*)(ab + ((16u*g)         ^ aswz));
        short8 a1 = *(const short8*)(ab + ((64u  + 16u*g)  ^ aswz));
        short8 a2 = *(const short8*)(ab + ((128u + 16u*g)  ^ aswz));
        short8 a3 = *(const short8*)(ab + ((192u + 16u*g)  ^ aswz));
        #pragma unroll
        for (int ntl = 0; ntl < 2; ntl++) {
            f32x4 acc = {bias1[ntl], bias1[ntl], bias1[ntl], bias1[ntl]};
            acc = __builtin_amdgcn_mfma_f32_16x16x32_bf16(a0, B2[ntl][0], acc, 0, 0, 0);
            acc = __builtin_amdgcn_mfma_f32_16x16x32_bf16(a1, B2[ntl][1], acc, 0, 0, 0);
            acc = __builtin_amdgcn_mfma_f32_16x16x32_bf16(a2, B2[ntl][2], acc, 0, 0, 0);
            acc = __builtin_amdgcn_mfma_f32_16x16x32_bf16(a3, B2[ntl][3], acc, 0, 0, 0);
            acc2[mt][ntl] = acc;
        }
    }
    __syncthreads();   // all h1 reads done -> safe to overwrite in place
    #pragma unroll
    for (int mt = 0; mt < 8; mt++) {
        #pragma unroll
        for (int ntl = 0; ntl < 2; ntl++) {
            const int n0 = (2*w + ntl) * 16;
            #pragma unroll
            for (int v = 0; v < 4; v++) {
                int row = mt*16 + 4*g + v;
                unsigned short hv = f2b_fast(fmaxf(acc2[mt][ntl][v], 0.f));
                *(unsigned short*)(hL + (((unsigned)(row*256 + (n0+ln)*2)) ^ ((unsigned)((row & 7) << 4)))) = hv;
            }
        }
    }
    // hoist B3 in the barrier shadow
    short8 B3[4];
    {
        const char* wb2 = (const char*)Wt2 + ln * 256 + 16*g;
        #pragma unroll
        for (int kk = 0; kk < 4; kk++) B3[kk] = *(const short8*)(wb2 + 64*kk);
    }
    __syncthreads();   // h2 complete

    // ---- layer 3 (M-split: rows 32w..32w+31) + sigmoid + ray-merged atomics ----
    {
        const float b2c = (ln < 3) ? b2[ln] : 0.f;
        #pragma unroll
        for (int mi = 0; mi < 2; mi++) {
            const int m0 = 32*w + 16*mi;
            const int arow = m0 + ln;
            const unsigned int aswz = (unsigned int)((arow & 7) << 4);
            const char* ab = hL + arow * 256;
            short8 a0 = *(const short8*)(ab + ((16u*g)         ^ aswz));
            short8 a1 = *(const short8*)(ab + ((64u  + 16u*g)  ^ aswz));
            short8 a2 = *(const short8*)(ab + ((128u + 16u*g)  ^ aswz));
            short8 a3 = *(const short8*)(ab + ((192u + 16u*g)  ^ aswz));
            f32x4 acc = {0.f, 0.f, 0.f, 0.f};
            acc = __builtin_amdgcn_mfma_f32_16x16x32_bf16(a0, B3[0], acc, 0, 0, 0);
            acc = __builtin_amdgcn_mfma_f32_16x16x32_bf16(a1, B3[1], acc, 0, 0, 0);
            acc = __builtin_amdgcn_mfma_f32_16x16x32_bf16(a2, B3[2], acc, 0, 0, 0);
            acc = __builtin_amdgcn_mfma_f32_16x16x32_bf16(a3, B3[3], acc, 0, 0, 0);

            float val[4];
            #pragma unroll
            for (int v = 0; v < 4; v++) {
                int row = m0 + 4*g + v;
                float logit = acc[v] + b2c + diffL[row*3 + ln];
                val[v] = (ln < 3) ? wgtL[row] / (1.f + expf(-logit)) : 0.f;
            }
            int r0t = ridL[m0], r15t = ridL[m0 + 15];
            if (r0t == r15t) {
                float s = val[0] + val[1] + val[2] + val[3];
                s += __shfl_xor(s, 16);
                s += __shfl_xor(s, 32);
                if (g == 0 && ln < 3) atomicAdd(out + 3*r0t + ln, s);
            } else if (ln < 3) {
                int rr = ridL[m0 + 4*g];
                float run = val[0];
                #pragma unroll
                for (int v = 1; v < 4; v++) {
                    int rv = ridL[m0 + 4*g + v];
                    if (rv == rr) run += val[v];
                    else { atomicAdd(out + 3*rr + ln, run); run = val[v]; rr = rv; }
                }
                atomicAdd(out + 3*rr + ln, run);
            }
        }
    }
}

// ================= legacy fused MLP (ultra fallback, 24B grid) =================
__global__ __launch_bounds__(256) void k_mlp_fused(
    const unsigned short* __restrict__ k0b, const float* __restrict__ xyz,
    const int* __restrict__ rid, const unsigned short* __restrict__ vemb,
    const float* __restrict__ wts,
    const unsigned short* __restrict__ Wt0, const float* __restrict__ b0,
    const unsigned short* __restrict__ Wt1, const float* __restrict__ b1,
    const unsigned short* __restrict__ Wt2, const float* __restrict__ b2,
    float* __restrict__ out, int M) {

    __shared__ char featL[128 * 128];
    __shared__ char hL[128 * 256];
    __shared__ float diffL[128 * 3];
    __shared__ float wgtL[128];
    __shared__ int   ridL[128];

    const int t = threadIdx.x;
    const int base = blockIdx.x * 128;
    const int p = t >> 1;
    const int dx = t & 1;
    const int i = base + p;

    float ch[12];
    #pragma unroll
    for (int c = 0; c < 12; c++) ch[c] = 0.f;

    if (i < M) {
        int ix, iy, iz; float fx, fy, fz;
        trisetup(xyz[3*i], xyz[3*i+1], xyz[3*i+2], ix, iy, iz, fx, fy, fz);
        float gz = 1.f - fz;
        float wx = dx ? fx : (1.f - fx);
        float wy0 = wx * (1.f - fy), wy1 = wx * fy;
        #pragma unroll
        for (int dy = 0; dy < 2; dy++) {
            float w2 = dy ? wy1 : wy0;
            size_t vox = (size_t)((ix + dx) * 160 + (iy + dy)) * 160 + iz;
            const char* pv = (const char*)k0b + vox * 24;
            u32x2 a0 = *(const u32x2*)(pv);
            u32x2 a1 = *(const u32x2*)(pv + 8);
            u32x2 a2 = *(const u32x2*)(pv + 16);
            u32x2 a3 = *(const u32x2*)(pv + 24);
            u32x2 a4 = *(const u32x2*)(pv + 32);
            u32x2 a5 = *(const u32x2*)(pv + 40);
            unsigned int u0[6] = {a0[0],a0[1],a1[0],a1[1],a2[0],a2[1]};
            unsigned int u1[6] = {a3[0],a3[1],a4[0],a4[1],a5[0],a5[1]};
            #pragma unroll
            for (int j = 0; j < 6; j++) {
                ch[2*j]   += w2 * (gz * blo(u0[j]) + fz * blo(u1[j]));
                ch[2*j+1] += w2 * (gz * bhi(u0[j]) + fz * bhi(u1[j]));
            }
        }
    }
    #pragma unroll
    for (int c = 0; c < 12; c++) ch[c] += __shfl_xor(ch[c], 1);

    if (dx == 0) {
        unsigned int fr[32];
        #pragma unroll
        for (int j = 19; j < 32; j++) fr[j] = 0u;
        float wpt = 0.f; int r = 0;
        if (i < M) {
            r = rid[i];
            wpt = wts[i];
            const unsigned int* vp = (const unsigned int*)(vemb + (size_t)r * 28);
            #pragma unroll
            for (int j = 0; j < 14; j++) fr[j] = vp[j];
            fr[14] = (unsigned int)f2b(ch[3]) | ((unsigned int)f2b(ch[4]) << 16);
            fr[15] = (unsigned int)f2b(ch[5]) | ((unsigned int)f2b(ch[6]) << 16);
            fr[16] = (unsigned int)f2b(ch[7]) | ((unsigned int)f2b(ch[8]) << 16);
            fr[17] = (unsigned int)f2b(ch[9]) | ((unsigned int)f2b(ch[10]) << 16);
            fr[18] = (unsigned int)f2b(ch[11]);
        } else {
            #pragma unroll
            for (int j = 0; j < 19; j++) fr[j] = 0u;
        }
        diffL[p*3 + 0] = ch[0];
        diffL[p*3 + 1] = ch[1];
        diffL[p*3 + 2] = ch[2];
        wgtL[p] = wpt;
        ridL[p] = r;
        char* fp = featL + p * 128;
        unsigned int rs = (unsigned int)((p & 7) << 4);
        #pragma unroll
        for (int j = 0; j < 8; j++)
            *(u32x4*)(fp + ((16u*j) ^ rs)) = *(u32x4*)(fr + 4*j);
    }
    __syncthreads();

    const int lane = t & 63;
    const int w = t >> 6;
    const int g = lane >> 4;
    const int ln = lane & 15;

    #pragma unroll
    for (int mi = 0; mi < 2; mi++) {
        const int m0 = 32*w + 16*mi;
        const int arow = m0 + ln;
        const unsigned int aswz = (unsigned int)((arow & 7) << 4);
        const char* ab = featL + arow * 128;
        short8 a0 = *(const short8*)(ab + ((16u*g)        ^ aswz));
        short8 a1 = *(const short8*)(ab + ((64u + 16u*g)  ^ aswz));
        #pragma unroll
        for (int nt = 0; nt < 8; nt++) {
            const int n0 = 16 * nt;
            float bias = b0[n0 + ln];
            f32x4 acc = {bias, bias, bias, bias};
            const char* wb = (const char*)Wt0 + (n0 + ln) * 128;
            acc = __builtin_amdgcn_mfma_f32_16x16x32_bf16(a0, *(const short8*)(wb + 16*g),      acc, 0, 0, 0);
            acc = __builtin_amdgcn_mfma_f32_16x16x32_bf16(a1, *(const short8*)(wb + 64 + 16*g), acc, 0, 0, 0);
            #pragma unroll
            for (int v = 0; v < 4; v++) {
                int row = m0 + 4*g + v;
                unsigned short hv = f2b_fast(fmaxf(acc[v], 0.f));
                *(unsigned short*)(hL + (((unsigned)(row*256 + (n0+ln)*2)) ^ ((unsigned)((row & 7) << 4)))) = hv;
            }
        }
    }

    #pragma unroll
    for (int mi = 0; mi < 2; mi++) {
        const int m0 = 32*w + 16*mi;
        const int arow = m0 + ln;
        const unsigned int aswz = (unsigned int)((arow & 7) << 4);
        const char* ab = hL + arow * 256;
        short8 a0 = *(const short8*)(ab + ((16u*g)         ^ aswz));
        short8 a1 = *(const short8*)(ab + ((64u  + 16u*g)  ^ aswz));
        short8 a2 = *(const short8*)(ab + ((128u + 16u*g)  ^ aswz));
        short8 a3 = *(const short8*)(ab + ((192u + 16u*g)  ^ aswz));
        #pragma unroll
        for (int nt = 0; nt < 8; nt++) {
            const int n0 = 16 * nt;
            float bias = b1[n0 + ln];
            f32x4 acc = {bias, bias, bias, bias};
            const char* wb = (const char*)Wt1 + (n0 + ln) * 256;
            acc = __builtin_amdgcn_mfma_f32_16x16x32_bf16(a0, *(const short8*)(wb + 16*g),       acc, 0, 0, 0);
            acc = __builtin_amdgcn_mfma_f32_16x16x32_bf16(a1, *(const short8*)(wb + 64 + 16*g),  acc, 0, 0, 0);
            acc = __builtin_amdgcn_mfma_f32_16x16x32_bf16(a2, *(const short8*)(wb + 128 + 16*g), acc, 0, 0, 0);
            acc = __builtin_amdgcn_mfma_f32_16x16x32_bf16(a3, *(const short8*)(wb + 192 + 16*g), acc, 0, 0, 0);
            #pragma unroll
            for (int v = 0; v < 4; v++) {
                int row = m0 + 4*g + v;
                unsigned short hv = f2b_fast(fmaxf(acc[v], 0.f));
                *(unsigned short*)(hL + (((unsigned)(row*256 + (n0+ln)*2)) ^ ((unsigned)((row & 7) << 4)))) = hv;
            }
        }
    }

    const float b2c = (ln < 3) ? b2[ln] : 0.f;
    #pragma unroll
    for (int mi = 0; mi < 2; mi++) {
        const int m0 = 32*w + 16*mi;
        const int arow = m0 + ln;
        const unsigned int aswz = (unsigned int)((arow & 7) << 4);
        const char* ab = hL + arow * 256;
        short8 a0 = *(const short8*)(ab + ((16u*g)         ^ aswz));
        short8 a1 = *(const short8*)(ab + ((64u  + 16u*g)  ^ aswz));
        short8 a2 = *(const short8*)(ab + ((128u + 16u*g)  ^ aswz));
        short8 a3 = *(const short8*)(ab + ((192u + 16u*g)  ^ aswz));
        f32x4 acc = {0.f, 0.f, 0.f, 0.f};
        const char* wb = (const char*)Wt2 + ln * 256;
        acc = __builtin_amdgcn_mfma_f32_16x16x32_bf16(a0, *(const short8*)(wb + 16*g),       acc, 0, 0, 0);
        acc = __builtin_amdgcn_mfma_f32_16x16x32_bf16(a1, *(const short8*)(wb + 64 + 16*g),  acc, 0, 0, 0);
        acc = __builtin_amdgcn_mfma_f32_16x16x32_bf16(a2, *(const short8*)(wb + 128 + 16*g), acc, 0, 0, 0);
        acc = __builtin_amdgcn_mfma_f32_16x16x32_bf16(a3, *(const short8*)(wb + 192 + 16*g), acc, 0, 0, 0);

        float val[4];
        #pragma unroll
        for (int v = 0; v < 4; v++) {
            int row = m0 + 4*g + v;
            float logit = acc[v] + b2c + diffL[row*3 + ln];
            val[v] = (ln < 3) ? wgtL[row] / (1.f + expf(-logit)) : 0.f;
        }
        int r0t = ridL[m0], r15t = ridL[m0 + 15];
        if (r0t == r15t) {
            float s = val[0] + val[1] + val[2] + val[3];
            s += __shfl_xor(s, 16);
            s += __shfl_xor(s, 32);
            if (g == 0 && ln < 3) atomicAdd(out + 3*r0t + ln, s);
        } else if (ln < 3) {
            int rr = ridL[m0 + 4*g];
            float run = val[0];
            #pragma unroll
            for (int v = 1; v < 4; v++) {
                int rv = ridL[m0 + 4*g + v];
                if (rv == rr) run += val[v];
                else { atomicAdd(out + 3*rr + ln, run); run = val[v]; rr = rv; }
            }
            atomicAdd(out + 3*rr + ln, run);
        }
    }
}

extern "C" void kernel_launch(void* const* d_in, const int* in_sizes, int n_in,
                              void* d_out, int out_size, void* d_ws, size_t ws_size,
                              hipStream_t stream) {
    const float* dg  = (const float*)d_in[0];
    const float* k0  = (const float*)d_in[1];
    const float* xyz = (const float*)d_in[2];
    const float* vd  = (const float*)d_in[3];
    const float* W0  = (const float*)d_in[4];
    const float* b0  = (const float*)d_in[5];
    const float* W1  = (const float*)d_in[6];
    const float* b1  = (const float*)d_in[7];
    const float* W2  = (const float*)d_in[8];
    const float* b2  = (const float*)d_in[9];
    const int*   rid = (const int*)d_in[10];
    float* out = (float*)d_out;

    const int M = in_sizes[2] / 3;
    const int R = in_sizes[3] / 3;

    const size_t wtb    = (size_t)(128*64 + 128*128 + 16*128) * 2;
    const size_t vembsz = (size_t)R * 28 * 2;
    const size_t alogsz = (size_t)M * 8;
    const size_t wtssz  = (size_t)M * 4;
    const size_t stsz   = (size_t)(R + 1) * 4;
    const size_t recsz  = (size_t)M * 32;
    const size_t fixed  = wtb + vembsz + alogsz + wtssz + stsz + 1024;

    const size_t need64 = (size_t)NVOX * 64 + fixed + recsz;
    const size_t need32 = (size_t)NVOX * 32 + fixed + recsz;
    const size_t need24 = (size_t)NVOX * 24 + fixed + recsz;

    int tier = (ws_size >= need64) ? 64 : (ws_size >= need32) ? 32 :
               (ws_size >= need24) ? 24 : 0;
    const size_t gridb = (tier == 64) ? (size_t)NVOX*64 : (tier == 32) ? (size_t)NVOX*32 : (size_t)NVOX*24;

    char* w = (char*)d_ws;
    unsigned int*   gridp = (unsigned int*)w;   w += gridb;
    unsigned short* Wt0   = (unsigned short*)w; w += 128*64*2;
    unsigned short* Wt1   = (unsigned short*)w; w += 128*128*2;
    unsigned short* Wt2   = (unsigned short*)w; w += 16*128*2;
    unsigned short* vembb = (unsigned short*)w; w += vembsz;
    float2* alog  = (float2*)w;  w += alogsz;
    float*  wts   = (float*)w;   w += wtssz;
    int*    starts= (int*)w;     w += stsz;
    w = (char*)(((size_t)w + 255) & ~(size_t)255);
    u32x4*  rec   = (u32x4*)w;

    const int gb = (NVOX + 255) / 256;
    k_wprep <<<dim3(64), dim3(256), 0, stream>>>(W0, W1, W2, Wt0, Wt1, Wt2);
    k_starts<<<dim3((R + 256) / 256), dim3(256), 0, stream>>>(rid, starts, M, R);
    k_vdemb <<<dim3((R + 255) / 256), dim3(256), 0, stream>>>(vd, vembb, R);

    if (tier > 0) {
        if (tier == 64)      k_t64<<<dim3(gb), dim3(256), 0, stream>>>(k0, dg, gridp);
        else if (tier == 32) k_t32<<<dim3(gb), dim3(256), 0, stream>>>(k0, dg, gridp);
        else                 k_t24<<<dim3(gb), dim3(256), 0, stream>>>(k0, gridp);

        const int gblocks = (2 * M + 255) / 256;
        if (tier == 64)
            k_gather<64><<<dim3(gblocks), dim3(256), 0, stream>>>(gridp, dg, xyz, rec, alog, M);
        else if (tier == 32)
            k_gather<32><<<dim3(gblocks), dim3(256), 0, stream>>>(gridp, dg, xyz, rec, alog, M);
        else
            k_gather<24><<<dim3(gblocks), dim3(256), 0, stream>>>(gridp, dg, xyz, rec, alog, M);

        k_scanw<<<dim3(((size_t)R * 64 + 255) / 256), dim3(256), 0, stream>>>(alog, starts, wts, out, R);
        k_mlp_s<<<dim3((M + 127) / 128), dim3(256), 0, stream>>>(rec, rid, vembb, wts,
                                                                 Wt0, b0, Wt1, b1, Wt2, b2, out, M);
    } else {
        k_t24    <<<dim3(gb), dim3(256), 0, stream>>>(k0, gridp);
        k_densityC<<<dim3((M + 255) / 256), dim3(256), 0, stream>>>(dg, xyz, alog, M);
        k_scanw  <<<dim3(((size_t)R * 64 + 255) / 256), dim3(256), 0, stream>>>(alog, starts, wts, out, R);
        k_mlp_fused<<<dim3((M + 127) / 128), dim3(256), 0, stream>>>((const unsigned short*)gridp, xyz, rid, vembb, wts,
                                                                     Wt0, b0, Wt1, b1, Wt2, b2, out, M);
    }
}

// Round 10
// 542.813 us; speedup vs baseline: 1.1263x; 1.1263x over previous
//
#include <hip/hip_runtime.h>

#define ACT_SHIFT (-4.5951198501345898f)   // log(1/(1-0.01) - 1)
#define DELTA 0.5f
#define XS 25600                            // 160*160
#define YS 160
#define NVOX 4096000

typedef __attribute__((ext_vector_type(8))) short short8;
typedef __attribute__((ext_vector_type(4))) float f32x4;
typedef __attribute__((ext_vector_type(2))) unsigned int u32x2;
typedef __attribute__((ext_vector_type(4))) unsigned int u32x4;

__device__ __forceinline__ float softplusf(float x) {
    return x > 20.f ? x : log1pf(expf(x));
}
__device__ __forceinline__ unsigned short f2b(float x) {        // RNE (prep paths)
    unsigned int u = __float_as_uint(x);
    u += 0x7fffu + ((u >> 16) & 1u);
    return (unsigned short)(u >> 16);
}
__device__ __forceinline__ unsigned short f2b_fast(float x) {   // round-half-up (verified r6)
    return (unsigned short)((__float_as_uint(x) + 0x8000u) >> 16);
}
__device__ __forceinline__ float blo(unsigned int u) { return __uint_as_float(u << 16); }
__device__ __forceinline__ float bhi(unsigned int u) { return __uint_as_float(u & 0xffff0000u); }

__device__ __forceinline__ void trisetup(float px, float py, float pz,
                                         int& ix, int& iy, int& iz,
                                         float& fx, float& fy, float& fz) {
    float sx = (px + 1.f) * 0.5f * 159.f;
    float sy = (py + 1.f) * 0.5f * 159.f;
    float sz = (pz + 1.f) * 0.5f * 159.f;
    sx = fminf(fmaxf(sx, 0.f), 159.f);
    sy = fminf(fmaxf(sy, 0.f), 159.f);
    sz = fminf(fmaxf(sz, 0.f), 159.f);
    ix = (int)sx; if (ix > 158) ix = 158;
    iy = (int)sy; if (iy > 158) iy = 158;
    iz = (int)sz; if (iz > 158) iz = 158;
    fx = sx - (float)ix;
    fy = sy - (float)iy;
    fz = sz - (float)iz;
}

// ================= grid builders =================
__global__ void k_t64(const float* __restrict__ k0, const float* __restrict__ dg,
                      unsigned int* __restrict__ grid) {
    int tid = blockIdx.x * 256 + threadIdx.x;
    if (tid >= NVOX) return;
    int z = tid % 160;
    int t1 = (z < 159) ? tid + 1 : tid;
    unsigned int w[16];
    #pragma unroll
    for (int j = 0; j < 6; j++) {
        w[j]   = (unsigned int)f2b(k0[(size_t)(2*j)*NVOX + tid]) | ((unsigned int)f2b(k0[(size_t)(2*j+1)*NVOX + tid]) << 16);
        w[6+j] = (unsigned int)f2b(k0[(size_t)(2*j)*NVOX + t1])  | ((unsigned int)f2b(k0[(size_t)(2*j+1)*NVOX + t1])  << 16);
    }
    w[12] = __float_as_uint(dg[tid]);
    w[13] = __float_as_uint(dg[t1]);
    w[14] = 0u; w[15] = 0u;
    u32x4* dst = (u32x4*)(grid + (size_t)tid * 16);
    dst[0] = *(u32x4*)(w);  dst[1] = *(u32x4*)(w+4);
    dst[2] = *(u32x4*)(w+8); dst[3] = *(u32x4*)(w+12);
}

__global__ void k_t32(const float* __restrict__ k0, const float* __restrict__ dg,
                      unsigned int* __restrict__ grid) {
    int tid = blockIdx.x * 256 + threadIdx.x;
    if (tid >= NVOX) return;
    unsigned int w[8];
    #pragma unroll
    for (int j = 0; j < 6; j++)
        w[j] = (unsigned int)f2b(k0[(size_t)(2*j)*NVOX + tid]) | ((unsigned int)f2b(k0[(size_t)(2*j+1)*NVOX + tid]) << 16);
    w[6] = __float_as_uint(dg[tid]);
    w[7] = 0u;
    u32x4* dst = (u32x4*)(grid + (size_t)tid * 8);
    dst[0] = *(u32x4*)(w); dst[1] = *(u32x4*)(w+4);
}
__global__ void k_t24(const float* __restrict__ k0, unsigned int* __restrict__ grid) {
    int tid = blockIdx.x * 256 + threadIdx.x;
    if (tid >= NVOX) return;
    unsigned int o[6];
    #pragma unroll
    for (int j = 0; j < 6; j++)
        o[j] = (unsigned int)f2b(k0[(size_t)(2*j)*NVOX + tid]) | ((unsigned int)f2b(k0[(size_t)(2*j+1)*NVOX + tid]) << 16);
    unsigned int* dst = grid + (size_t)tid * 6;
    #pragma unroll
    for (int j = 0; j < 6; j++) dst[j] = o[j];
}

// ================= small prep kernels =================
// Feature order: slots 0..26 = vd_emb, 27 = pad0, 28..36 = k0 ch3..11, 37..63 = 0
__global__ void k_wprep(const float* __restrict__ W0, const float* __restrict__ W1,
                        const float* __restrict__ W2,
                        unsigned short* __restrict__ Wt0, unsigned short* __restrict__ Wt1,
                        unsigned short* __restrict__ Wt2) {
    int id = blockIdx.x * 256 + threadIdx.x;
    if (id < 128 * 64) {
        int n = id >> 6, k = id & 63;
        float v = 0.f;
        if (k < 27)                 v = W0[(9 + k) * 128 + n];
        else if (k >= 28 && k < 37) v = W0[(k - 28) * 128 + n];
        Wt0[id] = f2b(v);
    }
    if (id < 128 * 128) { int n = id >> 7, k = id & 127; Wt1[id] = f2b(W1[k*128 + n]); }
    if (id < 16 * 128)  { int n = id >> 7, k = id & 127; Wt2[id] = (n < 3) ? f2b(W2[k*3 + n]) : 0; }
}

__global__ void k_starts(const int* __restrict__ rid, int* __restrict__ starts, int M, int R) {
    int r = blockIdx.x * blockDim.x + threadIdx.x;
    if (r > R) return;
    int lo = 0, hi = M;
    while (lo < hi) { int mid = (lo + hi) >> 1; if (rid[mid] < r) lo = mid + 1; else hi = mid; }
    starts[r] = lo;
}

__global__ void k_vdemb(const float* __restrict__ vd, unsigned short* __restrict__ emb, int R) {
    int r = blockIdx.x * blockDim.x + threadIdx.x;
    if (r >= R) return;
    float e[28];
    float v0 = vd[3*r], v1 = vd[3*r+1], v2 = vd[3*r+2];
    e[0] = v0; e[1] = v1; e[2] = v2;
    float v[3] = {v0, v1, v2};
    #pragma unroll
    for (int d = 0; d < 3; d++) {
        #pragma unroll
        for (int p = 0; p < 4; p++) {
            float a = v[d] * (float)(1 << p);
            e[3 + d*4 + p]  = sinf(a);
            e[15 + d*4 + p] = cosf(a);
        }
    }
    e[27] = 0.f;
    unsigned short* o = emb + r * 28;
    #pragma unroll
    for (int j = 0; j < 28; j++) o[j] = f2b(e[j]);
}

__global__ void k_densityC(const float* __restrict__ dg, const float* __restrict__ xyz,
                           float2* __restrict__ alog, int M) {
    int i = blockIdx.x * blockDim.x + threadIdx.x;
    if (i >= M) return;
    int ix, iy, iz; float fx, fy, fz;
    trisetup(xyz[3*i], xyz[3*i+1], xyz[3*i+2], ix, iy, iz, fx, fy, fz);
    const float* g = dg + ix * XS + iy * YS + iz;
    float gx = 1.f - fx, gy = 1.f - fy, gz = 1.f - fz;
    float v =
        gx * (gy * (gz * g[0]      + fz * g[1])      + fy * (gz * g[YS]      + fz * g[YS+1])) +
        fx * (gy * (gz * g[XS]     + fz * g[XS+1])   + fy * (gz * g[XS+YS]   + fz * g[XS+YS+1]));
    float sp = softplusf(v + ACT_SHIFT);
    float l  = -sp * DELTA;
    alog[i] = make_float2(1.f - expf(l), fmaxf(l, -15.9424285f));
}

// ================= gather: 2 threads/point =================
// rec[i] (32B): w0=(c3,c4) w1=(c5,c6) w2=(c7,c8) w3=(c9,c10) w4=(c11,0) w5..7=diff f32
template<int VOX>
__global__ __launch_bounds__(256) void k_gather(
    const unsigned int* __restrict__ grid, const float* __restrict__ dg,
    const float* __restrict__ xyz,
    u32x4* __restrict__ rec, float2* __restrict__ alog, int M) {

    const int t = blockIdx.x * 256 + threadIdx.x;
    const int p = t >> 1;
    const int dx = t & 1;
    if (p >= M) return;
    const int i = p;

    int ix, iy, iz; float fx, fy, fz;
    trisetup(xyz[3*i], xyz[3*i+1], xyz[3*i+2], ix, iy, iz, fx, fy, fz);
    float gz = 1.f - fz;
    float wx = dx ? fx : (1.f - fx);
    float wy[2] = {wx * (1.f - fy), wx * fy};

    float ch[12];
    #pragma unroll
    for (int c = 0; c < 12; c++) ch[c] = 0.f;
    float dd = 0.f;
    const int x = ix + dx;

    #pragma unroll
    for (int dy = 0; dy < 2; dy++) {
        float wc = wy[dy];
        size_t idx = (size_t)(x * 160 + (iy + dy)) * 160 + iz;
        if (VOX == 64) {
            const u32x4* e = (const u32x4*)(grid + idx * 16);
            u32x4 q0 = e[0], q1 = e[1], q2 = e[2], q3 = e[3];
            unsigned int wz[6]  = {q0[0],q0[1],q0[2],q0[3],q1[0],q1[1]};
            unsigned int wz1[6] = {q1[2],q1[3],q2[0],q2[1],q2[2],q2[3]};
            #pragma unroll
            for (int j = 0; j < 6; j++) {
                ch[2*j]   += wc * (gz * blo(wz[j]) + fz * blo(wz1[j]));
                ch[2*j+1] += wc * (gz * bhi(wz[j]) + fz * bhi(wz1[j]));
            }
            dd += wc * (gz * __uint_as_float(q3[0]) + fz * __uint_as_float(q3[1]));
        } else if (VOX == 32) {
            const u32x4* e0 = (const u32x4*)(grid + idx * 8);
            const u32x4* e1 = (const u32x4*)(grid + (idx + 1) * 8);
            u32x4 a0 = e0[0], a1 = e0[1], b0 = e1[0], b1 = e1[1];
            unsigned int wz[6]  = {a0[0],a0[1],a0[2],a0[3],a1[0],a1[1]};
            unsigned int wz1[6] = {b0[0],b0[1],b0[2],b0[3],b1[0],b1[1]};
            #pragma unroll
            for (int j = 0; j < 6; j++) {
                ch[2*j]   += wc * (gz * blo(wz[j]) + fz * blo(wz1[j]));
                ch[2*j+1] += wc * (gz * bhi(wz[j]) + fz * bhi(wz1[j]));
            }
            dd += wc * (gz * __uint_as_float(a1[2]) + fz * __uint_as_float(b1[2]));
        } else {
            const u32x2* e = (const u32x2*)(grid + idx * 6);
            u32x2 a0 = e[0], a1 = e[1], a2 = e[2], a3 = e[3], a4 = e[4], a5 = e[5];
            unsigned int wz[6]  = {a0[0],a0[1],a1[0],a1[1],a2[0],a2[1]};
            unsigned int wz1[6] = {a3[0],a3[1],a4[0],a4[1],a5[0],a5[1]};
            #pragma unroll
            for (int j = 0; j < 6; j++) {
                ch[2*j]   += wc * (gz * blo(wz[j]) + fz * blo(wz1[j]));
                ch[2*j+1] += wc * (gz * bhi(wz[j]) + fz * bhi(wz1[j]));
            }
            const float* dr = dg + (size_t)(x * 160 + (iy + dy)) * 160 + iz;
            dd += wc * (gz * dr[0] + fz * dr[1]);
        }
    }

    #pragma unroll
    for (int c = 0; c < 12; c++) ch[c] += __shfl_xor(ch[c], 1);
    dd += __shfl_xor(dd, 1);

    if (dx == 0) {
        unsigned int w[8];
        w[0] = (unsigned int)f2b(ch[3]) | ((unsigned int)f2b(ch[4]) << 16);
        w[1] = (unsigned int)f2b(ch[5]) | ((unsigned int)f2b(ch[6]) << 16);
        w[2] = (unsigned int)f2b(ch[7]) | ((unsigned int)f2b(ch[8]) << 16);
        w[3] = (unsigned int)f2b(ch[9]) | ((unsigned int)f2b(ch[10]) << 16);
        w[4] = (unsigned int)f2b(ch[11]);
        w[5] = __float_as_uint(ch[0]);
        w[6] = __float_as_uint(ch[1]);
        w[7] = __float_as_uint(ch[2]);
        rec[(size_t)i*2]     = *(u32x4*)(w);
        rec[(size_t)i*2 + 1] = *(u32x4*)(w + 4);
    } else {
        float sp = softplusf(dd + ACT_SHIFT);
        float l  = -sp * DELTA;
        alog[i] = make_float2(1.f - expf(l), fmaxf(l, -15.9424285f));
    }
}

// ================= wave-per-ray scan =================
__global__ void k_scanw(const float2* __restrict__ alog, const int* __restrict__ starts,
                        float* __restrict__ wts, float* __restrict__ out, int R) {
    const int r = (blockIdx.x * blockDim.x + threadIdx.x) >> 6;
    const int lane = threadIdx.x & 63;
    if (r >= R) return;
    const int s = starts[r], e = starts[r + 1];
    float carry = 0.f;
    for (int i0 = s; i0 < e; i0 += 64) {
        int idx = i0 + lane;
        bool pr = idx < e;
        float a = 0.f, x = 0.f;
        if (pr) { float2 v = alog[idx]; a = v.x; x = v.y; }
        float incl = x;
        #pragma unroll
        for (int d = 1; d < 64; d <<= 1) {
            float tv = __shfl_up(incl, d);
            if (lane >= d) incl += tv;
        }
        if (pr) wts[idx] = a * expf(carry + (incl - x));
        carry += __shfl(incl, 63);
    }
    float ainv = expf(carry);
    if (lane == 0) { out[3*r] = ainv; out[3*r+1] = ainv; out[3*r+2] = ainv; }
}

// ================= MFMA MLP v5: merged LDS + phase-split 32-reg accumulators =========
// feat in hL[0,16KB) (rows 0-127 x 128B, XOR swz). h rows 64-127 live at [16KB,32KB):
// NO aliasing with feat -> L1 upper half stores need no barrier. Max acc live = 32 regs.
__global__ __launch_bounds__(256, 4) void k_mlp_s(
    const u32x4* __restrict__ rec, const int* __restrict__ rid,
    const unsigned short* __restrict__ vemb, const float* __restrict__ wts,
    const unsigned short* __restrict__ Wt0, const float* __restrict__ b0,
    const unsigned short* __restrict__ Wt1, const float* __restrict__ b1,
    const unsigned short* __restrict__ Wt2, const float* __restrict__ b2,
    float* __restrict__ out, int M) {

    __shared__ char hL[128 * 256];     // 32 KB; feat aliased into first 16 KB
    __shared__ float diffL[128 * 3];
    __shared__ float wgtL[128];
    __shared__ int   ridL[128];

    const int t = threadIdx.x;
    const int base = blockIdx.x * 128;

    // ---- staging: feat rows into hL[0..16KB) (row-major, swizzled) ----
    if (t < 128) {
        const int i = base + t;
        unsigned int fr[32];
        #pragma unroll
        for (int j = 19; j < 32; j++) fr[j] = 0u;
        float wpt = 0.f; int r = 0;
        float d0 = 0.f, d1 = 0.f, d2 = 0.f;
        if (i < M) {
            u32x4 r0 = rec[(size_t)i*2];
            u32x4 r1 = rec[(size_t)i*2 + 1];
            r = rid[i];
            wpt = wts[i];
            const unsigned int* vp = (const unsigned int*)(vemb + (size_t)r * 28);
            #pragma unroll
            for (int j = 0; j < 14; j++) fr[j] = vp[j];   // vemb (slot 27 pad=0)
            fr[14] = r0[0]; fr[15] = r0[1]; fr[16] = r0[2]; fr[17] = r0[3];
            fr[18] = r1[0] & 0xffffu;                      // (c11, 0)
            d0 = __uint_as_float(r1[1]); d1 = __uint_as_float(r1[2]); d2 = __uint_as_float(r1[3]);
        } else {
            #pragma unroll
            for (int j = 0; j < 19; j++) fr[j] = 0u;
        }
        diffL[t*3 + 0] = d0; diffL[t*3 + 1] = d1; diffL[t*3 + 2] = d2;
        wgtL[t] = wpt;
        ridL[t] = r;
        char* fp = hL + t * 128;
        unsigned int rs = (unsigned int)((t & 7) << 4);
        #pragma unroll
        for (int j = 0; j < 8; j++)
            *(u32x4*)(fp + ((16u*j) ^ rs)) = *(u32x4*)(fr + 4*j);
    }

    const int lane = t & 63;
    const int w = t >> 6;
    const int g = lane >> 4;
    const int ln = lane & 15;

    // ---- hoist B1 ----
    short8 B1[2][2];
    float bias0[2];
    #pragma unroll
    for (int ntl = 0; ntl < 2; ntl++) {
        const int n0 = (2*w + ntl) * 16;
        const char* wb0 = (const char*)Wt0 + (n0 + ln) * 128 + 16*g;
        B1[ntl][0] = *(const short8*)(wb0);
        B1[ntl][1] = *(const short8*)(wb0 + 64);
        bias0[ntl] = b0[n0 + ln];
    }
    __syncthreads();   // feat staged

    // ---- L1 upper half (mt=4..7): compute + store immediately (no alias w/ feat) ----
    {
        f32x4 acc[4][2];
        #pragma unroll
        for (int mtl = 0; mtl < 4; mtl++) {
            const int arow = (4 + mtl)*16 + ln;
            const unsigned int aswz = (unsigned int)((arow & 7) << 4);
            const char* ab = hL + arow * 128;
            short8 a0 = *(const short8*)(ab + ((16u*g)        ^ aswz));
            short8 a1 = *(const short8*)(ab + ((64u + 16u*g)  ^ aswz));
            #pragma unroll
            for (int ntl = 0; ntl < 2; ntl++) {
                f32x4 a = {bias0[ntl], bias0[ntl], bias0[ntl], bias0[ntl]};
                a = __builtin_amdgcn_mfma_f32_16x16x32_bf16(a0, B1[ntl][0], a, 0, 0, 0);
                a = __builtin_amdgcn_mfma_f32_16x16x32_bf16(a1, B1[ntl][1], a, 0, 0, 0);
                acc[mtl][ntl] = a;
            }
        }
        #pragma unroll
        for (int mtl = 0; mtl < 4; mtl++) {
            #pragma unroll
            for (int ntl = 0; ntl < 2; ntl++) {
                const int n0 = (2*w + ntl) * 16;
                #pragma unroll
                for (int v = 0; v < 4; v++) {
                    int row = (4 + mtl)*16 + 4*g + v;   // rows 64..127 -> bytes 16K..32K
                    unsigned short hv = f2b_fast(fmaxf(acc[mtl][ntl][v], 0.f));
                    *(unsigned short*)(hL + (((unsigned)(row*256 + (n0+ln)*2)) ^ ((unsigned)((row & 7) << 4)))) = hv;
                }
            }
        }
    }

    // ---- L1 lower half (mt=0..3): compute into regs; store after barrier ----
    f32x4 accL[4][2];
    #pragma unroll
    for (int mtl = 0; mtl < 4; mtl++) {
        const int arow = mtl*16 + ln;
        const unsigned int aswz = (unsigned int)((arow & 7) << 4);
        const char* ab = hL + arow * 128;
        short8 a0 = *(const short8*)(ab + ((16u*g)        ^ aswz));
        short8 a1 = *(const short8*)(ab + ((64u + 16u*g)  ^ aswz));
        #pragma unroll
        for (int ntl = 0; ntl < 2; ntl++) {
            f32x4 a = {bias0[ntl], bias0[ntl], bias0[ntl], bias0[ntl]};
            a = __builtin_amdgcn_mfma_f32_16x16x32_bf16(a0, B1[ntl][0], a, 0, 0, 0);
            a = __builtin_amdgcn_mfma_f32_16x16x32_bf16(a1, B1[ntl][1], a, 0, 0, 0);
            accL[mtl][ntl] = a;
        }
    }
    // hoist B2 in the shadow
    short8 B2[2][4];
    float bias1[2];
    #pragma unroll
    for (int ntl = 0; ntl < 2; ntl++) {
        const int n0 = (2*w + ntl) * 16;
        const char* wb1 = (const char*)Wt1 + (n0 + ln) * 256 + 16*g;
        #pragma unroll
        for (int kk = 0; kk < 4; kk++)
            B2[ntl][kk] = *(const short8*)(wb1 + 64*kk);
        bias1[ntl] = b1[n0 + ln];
    }
    __syncthreads();   // all feat reads done -> safe to overwrite feat region
    #pragma unroll
    for (int mtl = 0; mtl < 4; mtl++) {
        #pragma unroll
        for (int ntl = 0; ntl < 2; ntl++) {
            const int n0 = (2*w + ntl) * 16;
            #pragma unroll
            for (int v = 0; v < 4; v++) {
                int row = mtl*16 + 4*g + v;             // rows 0..63 -> bytes 0..16K
                unsigned short hv = f2b_fast(fmaxf(accL[mtl][ntl][v], 0.f));
                *(unsigned short*)(hL + (((unsigned)(row*256 + (n0+ln)*2)) ^ ((unsigned)((row & 7) << 4)))) = hv;
            }
        }
    }
    __syncthreads();   // h1 fully visible

    // ---- L2 half A (mt=0..3): read rows 0..63, barrier, store h2 rows 0..63 ----
    {
        f32x4 acc[4][2];
        #pragma unroll
        for (int mtl = 0; mtl < 4; mtl++) {
            const int arow = mtl*16 + ln;
            const unsigned int aswz = (unsigned int)((arow & 7) << 4);
            const char* ab = hL + arow * 256;
            short8 a0 = *(const short8*)(ab + ((16u*g)         ^ aswz));
            short8 a1 = *(const short8*)(ab + ((64u  + 16u*g)  ^ aswz));
            short8 a2 = *(const short8*)(ab + ((128u + 16u*g)  ^ aswz));
            short8 a3 = *(const short8*)(ab + ((192u + 16u*g)  ^ aswz));
            #pragma unroll
            for (int ntl = 0; ntl < 2; ntl++) {
                f32x4 a = {bias1[ntl], bias1[ntl], bias1[ntl], bias1[ntl]};
                a = __builtin_amdgcn_mfma_f32_16x16x32_bf16(a0, B2[ntl][0], a, 0, 0, 0);
                a = __builtin_amdgcn_mfma_f32_16x16x32_bf16(a1, B2[ntl][1], a, 0, 0, 0);
                a = __builtin_amdgcn_mfma_f32_16x16x32_bf16(a2, B2[ntl][2], a, 0, 0, 0);
                a = __builtin_amdgcn_mfma_f32_16x16x32_bf16(a3, B2[ntl][3], a, 0, 0, 0);
                acc[mtl][ntl] = a;
            }
        }
        __syncthreads();   // all reads of rows 0..63 done
        #pragma unroll
        for (int mtl = 0; mtl < 4; mtl++) {
            #pragma unroll
            for (int ntl = 0; ntl < 2; ntl++) {
                const int n0 = (2*w + ntl) * 16;
                #pragma unroll
                for (int v = 0; v < 4; v++) {
                    int row = mtl*16 + 4*g + v;
                    unsigned short hv = f2b_fast(fmaxf(acc[mtl][ntl][v], 0.f));
                    *(unsigned short*)(hL + (((unsigned)(row*256 + (n0+ln)*2)) ^ ((unsigned)((row & 7) << 4)))) = hv;
                }
            }
        }
    }

    // ---- L2 half B (mt=4..7): reads rows 64..127 (disjoint from half-A stores) ----
    {
        f32x4 acc[4][2];
        #pragma unroll
        for (int mtl = 0; mtl < 4; mtl++) {
            const int arow = (4 + mtl)*16 + ln;
            const unsigned int aswz = (unsigned int)((arow & 7) << 4);
            const char* ab = hL + arow * 256;
            short8 a0 = *(const short8*)(ab + ((16u*g)         ^ aswz));
            short8 a1 = *(const short8*)(ab + ((64u  + 16u*g)  ^ aswz));
            short8 a2 = *(const short8*)(ab + ((128u + 16u*g)  ^ aswz));
            short8 a3 = *(const short8*)(ab + ((192u + 16u*g)  ^ aswz));
            #pragma unroll
            for (int ntl = 0; ntl < 2; ntl++) {
                f32x4 a = {bias1[ntl], bias1[ntl], bias1[ntl], bias1[ntl]};
                a = __builtin_amdgcn_mfma_f32_16x16x32_bf16(a0, B2[ntl][0], a, 0, 0, 0);
                a = __builtin_amdgcn_mfma_f32_16x16x32_bf16(a1, B2[ntl][1], a, 0, 0, 0);
                a = __builtin_amdgcn_mfma_f32_16x16x32_bf16(a2, B2[ntl][2], a, 0, 0, 0);
                a = __builtin_amdgcn_mfma_f32_16x16x32_bf16(a3, B2[ntl][3], a, 0, 0, 0);
                acc[mtl][ntl] = a;
            }
        }
        __syncthreads();   // all reads of rows 64..127 done
        #pragma unroll
        for (int mtl = 0; mtl < 4; mtl++) {
            #pragma unroll
            for (int ntl = 0; ntl < 2; ntl++) {
                const int n0 = (2*w + ntl) * 16;
                #pragma unroll
                for (int v = 0; v < 4; v++) {
                    int row = (4 + mtl)*16 + 4*g + v;
                    unsigned short hv = f2b_fast(fmaxf(acc[mtl][ntl][v], 0.f));
                    *(unsigned short*)(hL + (((unsigned)(row*256 + (n0+ln)*2)) ^ ((unsigned)((row & 7) << 4)))) = hv;
                }
            }
        }
    }

    // hoist B3 in the barrier shadow
    short8 B3[4];
    {
        const char* wb2 = (const char*)Wt2 + ln * 256 + 16*g;
        #pragma unroll
        for (int kk = 0; kk < 4; kk++) B3[kk] = *(const short8*)(wb2 + 64*kk);
    }
    __syncthreads();   // h2 complete

    // ---- layer 3 (M-split: rows 32w..32w+31) + sigmoid + ray-merged atomics ----
    {
        const float b2c = (ln < 3) ? b2[ln] : 0.f;
        #pragma unroll
        for (int mi = 0; mi < 2; mi++) {
            const int m0 = 32*w + 16*mi;
            const int arow = m0 + ln;
            const unsigned int aswz = (unsigned int)((arow & 7) << 4);
            const char* ab = hL + arow * 256;
            short8 a0 = *(const short8*)(ab + ((16u*g)         ^ aswz));
            short8 a1 = *(const short8*)(ab + ((64u  + 16u*g)  ^ aswz));
            short8 a2 = *(const short8*)(ab + ((128u + 16u*g)  ^ aswz));
            short8 a3 = *(const short8*)(ab + ((192u + 16u*g)  ^ aswz));
            f32x4 acc = {0.f, 0.f, 0.f, 0.f};
            acc = __builtin_amdgcn_mfma_f32_16x16x32_bf16(a0, B3[0], acc, 0, 0, 0);
            acc = __builtin_amdgcn_mfma_f32_16x16x32_bf16(a1, B3[1], acc, 0, 0, 0);
            acc = __builtin_amdgcn_mfma_f32_16x16x32_bf16(a2, B3[2], acc, 0, 0, 0);
            acc = __builtin_amdgcn_mfma_f32_16x16x32_bf16(a3, B3[3], acc, 0, 0, 0);

            float val[4];
            #pragma unroll
            for (int v = 0; v < 4; v++) {
                int row = m0 + 4*g + v;
                float logit = acc[v] + b2c + diffL[row*3 + ln];
                val[v] = (ln < 3) ? wgtL[row] / (1.f + expf(-logit)) : 0.f;
            }
            int r0t = ridL[m0], r15t = ridL[m0 + 15];
            if (r0t == r15t) {
                float s = val[0] + val[1] + val[2] + val[3];
                s += __shfl_xor(s, 16);
                s += __shfl_xor(s, 32);
                if (g == 0 && ln < 3) atomicAdd(out + 3*r0t + ln, s);
            } else if (ln < 3) {
                int rr = ridL[m0 + 4*g];
                float run = val[0];
                #pragma unroll
                for (int v = 1; v < 4; v++) {
                    int rv = ridL[m0 + 4*g + v];
                    if (rv == rr) run += val[v];
                    else { atomicAdd(out + 3*rr + ln, run); run = val[v]; rr = rv; }
                }
                atomicAdd(out + 3*rr + ln, run);
            }
        }
    }
}

// ================= legacy fused MLP (ultra fallback, 24B grid) =================
__global__ __launch_bounds__(256) void k_mlp_fused(
    const unsigned short* __restrict__ k0b, const float* __restrict__ xyz,
    const int* __restrict__ rid, const unsigned short* __restrict__ vemb,
    const float* __restrict__ wts,
    const unsigned short* __restrict__ Wt0, const float* __restrict__ b0,
    const unsigned short* __restrict__ Wt1, const float* __restrict__ b1,
    const unsigned short* __restrict__ Wt2, const float* __restrict__ b2,
    float* __restrict__ out, int M) {

    __shared__ char featL[128 * 128];
    __shared__ char hL[128 * 256];
    __shared__ float diffL[128 * 3];
    __shared__ float wgtL[128];
    __shared__ int   ridL[128];

    const int t = threadIdx.x;
    const int base = blockIdx.x * 128;
    const int p = t >> 1;
    const int dx = t & 1;
    const int i = base + p;

    float ch[12];
    #pragma unroll
    for (int c = 0; c < 12; c++) ch[c] = 0.f;

    if (i < M) {
        int ix, iy, iz; float fx, fy, fz;
        trisetup(xyz[3*i], xyz[3*i+1], xyz[3*i+2], ix, iy, iz, fx, fy, fz);
        float gz = 1.f - fz;
        float wx = dx ? fx : (1.f - fx);
        float wy0 = wx * (1.f - fy), wy1 = wx * fy;
        #pragma unroll
        for (int dy = 0; dy < 2; dy++) {
            float w2 = dy ? wy1 : wy0;
            size_t vox = (size_t)((ix + dx) * 160 + (iy + dy)) * 160 + iz;
            const char* pv = (const char*)k0b + vox * 24;
            u32x2 a0 = *(const u32x2*)(pv);
            u32x2 a1 = *(const u32x2*)(pv + 8);
            u32x2 a2 = *(const u32x2*)(pv + 16);
            u32x2 a3 = *(const u32x2*)(pv + 24);
            u32x2 a4 = *(const u32x2*)(pv + 32);
            u32x2 a5 = *(const u32x2*)(pv + 40);
            unsigned int u0[6] = {a0[0],a0[1],a1[0],a1[1],a2[0],a2[1]};
            unsigned int u1[6] = {a3[0],a3[1],a4[0],a4[1],a5[0],a5[1]};
            #pragma unroll
            for (int j = 0; j < 6; j++) {
                ch[2*j]   += w2 * (gz * blo(u0[j]) + fz * blo(u1[j]));
                ch[2*j+1] += w2 * (gz * bhi(u0[j]) + fz * bhi(u1[j]));
            }
        }
    }
    #pragma unroll
    for (int c = 0; c < 12; c++) ch[c] += __shfl_xor(ch[c], 1);

    if (dx == 0) {
        unsigned int fr[32];
        #pragma unroll
        for (int j = 19; j < 32; j++) fr[j] = 0u;
        float wpt = 0.f; int r = 0;
        if (i < M) {
            r = rid[i];
            wpt = wts[i];
            const unsigned int* vp = (const unsigned int*)(vemb + (size_t)r * 28);
            #pragma unroll
            for (int j = 0; j < 14; j++) fr[j] = vp[j];
            fr[14] = (unsigned int)f2b(ch[3]) | ((unsigned int)f2b(ch[4]) << 16);
            fr[15] = (unsigned int)f2b(ch[5]) | ((unsigned int)f2b(ch[6]) << 16);
            fr[16] = (unsigned int)f2b(ch[7]) | ((unsigned int)f2b(ch[8]) << 16);
            fr[17] = (unsigned int)f2b(ch[9]) | ((unsigned int)f2b(ch[10]) << 16);
            fr[18] = (unsigned int)f2b(ch[11]);
        } else {
            #pragma unroll
            for (int j = 0; j < 19; j++) fr[j] = 0u;
        }
        diffL[p*3 + 0] = ch[0];
        diffL[p*3 + 1] = ch[1];
        diffL[p*3 + 2] = ch[2];
        wgtL[p] = wpt;
        ridL[p] = r;
        char* fp = featL + p * 128;
        unsigned int rs = (unsigned int)((p & 7) << 4);
        #pragma unroll
        for (int j = 0; j < 8; j++)
            *(u32x4*)(fp + ((16u*j) ^ rs)) = *(u32x4*)(fr + 4*j);
    }
    __syncthreads();

    const int lane = t & 63;
    const int w = t >> 6;
    const int g = lane >> 4;
    const int ln = lane & 15;

    #pragma unroll
    for (int mi = 0; mi < 2; mi++) {
        const int m0 = 32*w + 16*mi;
        const int arow = m0 + ln;
        const unsigned int aswz = (unsigned int)((arow & 7) << 4);
        const char* ab = featL + arow * 128;
        short8 a0 = *(const short8*)(ab + ((16u*g)        ^ aswz));
        short8 a1 = *(const short8*)(ab + ((64u + 16u*g)  ^ aswz));
        #pragma unroll
        for (int nt = 0; nt < 8; nt++) {
            const int n0 = 16 * nt;
            float bias = b0[n0 + ln];
            f32x4 acc = {bias, bias, bias, bias};
            const char* wb = (const char*)Wt0 + (n0 + ln) * 128;
            acc = __builtin_amdgcn_mfma_f32_16x16x32_bf16(a0, *(const short8*)(wb + 16*g),      acc, 0, 0, 0);
            acc = __builtin_amdgcn_mfma_f32_16x16x32_bf16(a1, *(const short8*)(wb + 64 + 16*g), acc, 0, 0, 0);
            #pragma unroll
            for (int v = 0; v < 4; v++) {
                int row = m0 + 4*g + v;
                unsigned short hv = f2b_fast(fmaxf(acc[v], 0.f));
                *(unsigned short*)(hL + (((unsigned)(row*256 + (n0+ln)*2)) ^ ((unsigned)((row & 7) << 4)))) = hv;
            }
        }
    }

    #pragma unroll
    for (int mi = 0; mi < 2; mi++) {
        const int m0 = 32*w + 16*mi;
        const int arow = m0 + ln;
        const unsigned int aswz = (unsigned int)((arow & 7) << 4);
        const char* ab = hL + arow * 256;
        short8 a0 = *(const short8*)(ab + ((16u*g)         ^ aswz));
        short8 a1 = *(const short8*)(ab + ((64u  + 16u*g)  ^ aswz));
        short8 a2 = *(const short8*)(ab + ((128u + 16u*g)  ^ aswz));
        short8 a3 = *(const short8*)(ab + ((192u + 16u*g)  ^ aswz));
        #pragma unroll
        for (int nt = 0; nt < 8; nt++) {
            const int n0 = 16 * nt;
            float bias = b1[n0 + ln];
            f32x4 acc = {bias, bias, bias, bias};
            const char* wb = (const char*)Wt1 + (n0 + ln) * 256;
            acc = __builtin_amdgcn_mfma_f32_16x16x32_bf16(a0, *(const short8*)(wb + 16*g),       acc, 0, 0, 0);
            acc = __builtin_amdgcn_mfma_f32_16x16x32_bf16(a1, *(const short8*)(wb + 64 + 16*g),  acc, 0, 0, 0);
            acc = __builtin_amdgcn_mfma_f32_16x16x32_bf16(a2, *(const short8*)(wb + 128 + 16*g), acc, 0, 0, 0);
            acc = __builtin_amdgcn_mfma_f32_16x16x32_bf16(a3, *(const short8*)(wb + 192 + 16*g), acc, 0, 0, 0);
            #pragma unroll
            for (int v = 0; v < 4; v++) {
                int row = m0 + 4*g + v;
                unsigned short hv = f2b_fast(fmaxf(acc[v], 0.f));
                *(unsigned short*)(hL + (((unsigned)(row*256 + (n0+ln)*2)) ^ ((unsigned)((row & 7) << 4)))) = hv;
            }
        }
    }

    const float b2c = (ln < 3) ? b2[ln] : 0.f;
    #pragma unroll
    for (int mi = 0; mi < 2; mi++) {
        const int m0 = 32*w + 16*mi;
        const int arow = m0 + ln;
        const unsigned int aswz = (unsigned int)((arow & 7) << 4);
        const char* ab = hL + arow * 256;
        short8 a0 = *(const short8*)(ab + ((16u*g)         ^ aswz));
        short8 a1 = *(const short8*)(ab + ((64u  + 16u*g)  ^ aswz));
        short8 a2 = *(const short8*)(ab + ((128u + 16u*g)  ^ aswz));
        short8 a3 = *(const short8*)(ab + ((192u + 16u*g)  ^ aswz));
        f32x4 acc = {0.f, 0.f, 0.f, 0.f};
        const char* wb = (const char*)Wt2 + ln * 256;
        acc = __builtin_amdgcn_mfma_f32_16x16x32_bf16(a0, *(const short8*)(wb + 16*g),       acc, 0, 0, 0);
        acc = __builtin_amdgcn_mfma_f32_16x16x32_bf16(a1, *(const short8*)(wb + 64 + 16*g),  acc, 0, 0, 0);
        acc = __builtin_amdgcn_mfma_f32_16x16x32_bf16(a2, *(const short8*)(wb + 128 + 16*g), acc, 0, 0, 0);
        acc = __builtin_amdgcn_mfma_f32_16x16x32_bf16(a3, *(const short8*)(wb + 192 + 16*g), acc, 0, 0, 0);

        float val[4];
        #pragma unroll
        for (int v = 0; v < 4; v++) {
            int row = m0 + 4*g + v;
            float logit = acc[v] + b2c + diffL[row*3 + ln];
            val[v] = (ln < 3) ? wgtL[row] / (1.f + expf(-logit)) : 0.f;
        }
        int r0t = ridL[m0], r15t = ridL[m0 + 15];
        if (r0t == r15t) {
            float s = val[0] + val[1] + val[2] + val[3];
            s += __shfl_xor(s, 16);
            s += __shfl_xor(s, 32);
            if (g == 0 && ln < 3) atomicAdd(out + 3*r0t + ln, s);
        } else if (ln < 3) {
            int rr = ridL[m0 + 4*g];
            float run = val[0];
            #pragma unroll
            for (int v = 1; v < 4; v++) {
                int rv = ridL[m0 + 4*g + v];
                if (rv == rr) run += val[v];
                else { atomicAdd(out + 3*rr + ln, run); run = val[v]; rr = rv; }
            }
            atomicAdd(out + 3*rr + ln, run);
        }
    }
}

extern "C" void kernel_launch(void* const* d_in, const int* in_sizes, int n_in,
                              void* d_out, int out_size, void* d_ws, size_t ws_size,
                              hipStream_t stream) {
    const float* dg  = (const float*)d_in[0];
    const float* k0  = (const float*)d_in[1];
    const float* xyz = (const float*)d_in[2];
    const float* vd  = (const float*)d_in[3];
    const float* W0  = (const float*)d_in[4];
    const float* b0  = (const float*)d_in[5];
    const float* W1  = (const float*)d_in[6];
    const float* b1  = (const float*)d_in[7];
    const float* W2  = (const float*)d_in[8];
    const float* b2  = (const float*)d_in[9];
    const int*   rid = (const int*)d_in[10];
    float* out = (float*)d_out;

    const int M = in_sizes[2] / 3;
    const int R = in_sizes[3] / 3;

    const size_t wtb    = (size_t)(128*64 + 128*128 + 16*128) * 2;
    const size_t vembsz = (size_t)R * 28 * 2;
    const size_t alogsz = (size_t)M * 8;
    const size_t wtssz  = (size_t)M * 4;
    const size_t stsz   = (size_t)(R + 1) * 4;
    const size_t recsz  = (size_t)M * 32;
    const size_t fixed  = wtb + vembsz + alogsz + wtssz + stsz + 1024;

    const size_t need64 = (size_t)NVOX * 64 + fixed + recsz;
    const size_t need32 = (size_t)NVOX * 32 + fixed + recsz;
    const size_t need24 = (size_t)NVOX * 24 + fixed + recsz;

    int tier = (ws_size >= need64) ? 64 : (ws_size >= need32) ? 32 :
               (ws_size >= need24) ? 24 : 0;
    const size_t gridb = (tier == 64) ? (size_t)NVOX*64 : (tier == 32) ? (size_t)NVOX*32 : (size_t)NVOX*24;

    char* w = (char*)d_ws;
    unsigned int*   gridp = (unsigned int*)w;   w += gridb;
    unsigned short* Wt0   = (unsigned short*)w; w += 128*64*2;
    unsigned short* Wt1   = (unsigned short*)w; w += 128*128*2;
    unsigned short* Wt2   = (unsigned short*)w; w += 16*128*2;
    unsigned short* vembb = (unsigned short*)w; w += vembsz;
    float2* alog  = (float2*)w;  w += alogsz;
    float*  wts   = (float*)w;   w += wtssz;
    int*    starts= (int*)w;     w += stsz;
    w = (char*)(((size_t)w + 255) & ~(size_t)255);
    u32x4*  rec   = (u32x4*)w;

    const int gb = (NVOX + 255) / 256;
    k_wprep <<<dim3(64), dim3(256), 0, stream>>>(W0, W1, W2, Wt0, Wt1, Wt2);
    k_starts<<<dim3((R + 256) / 256), dim3(256), 0, stream>>>(rid, starts, M, R);
    k_vdemb <<<dim3((R + 255) / 256), dim3(256), 0, stream>>>(vd, vembb, R);

    if (tier > 0) {
        if (tier == 64)      k_t64<<<dim3(gb), dim3(256), 0, stream>>>(k0, dg, gridp);
        else if (tier == 32) k_t32<<<dim3(gb), dim3(256), 0, stream>>>(k0, dg, gridp);
        else                 k_t24<<<dim3(gb), dim3(256), 0, stream>>>(k0, gridp);

        const int gblocks = (2 * M + 255) / 256;
        if (tier == 64)
            k_gather<64><<<dim3(gblocks), dim3(256), 0, stream>>>(gridp, dg, xyz, rec, alog, M);
        else if (tier == 32)
            k_gather<32><<<dim3(gblocks), dim3(256), 0, stream>>>(gridp, dg, xyz, rec, alog, M);
        else
            k_gather<24><<<dim3(gblocks), dim3(256), 0, stream>>>(gridp, dg, xyz, rec, alog, M);

        k_scanw<<<dim3(((size_t)R * 64 + 255) / 256), dim3(256), 0, stream>>>(alog, starts, wts, out, R);
        k_mlp_s<<<dim3((M + 127) / 128), dim3(256), 0, stream>>>(rec, rid, vembb, wts,
                                                                 Wt0, b0, Wt1, b1, Wt2, b2, out, M);
    } else {
        k_t24    <<<dim3(gb), dim3(256), 0, stream>>>(k0, gridp);
        k_densityC<<<dim3((M + 255) / 256), dim3(256), 0, stream>>>(dg, xyz, alog, M);
        k_scanw  <<<dim3(((size_t)R * 64 + 255) / 256), dim3(256), 0, stream>>>(alog, starts, wts, out, R);
        k_mlp_fused<<<dim3((M + 127) / 128), dim3(256), 0, stream>>>((const unsigned short*)gridp, xyz, rid, vembb, wts,
                                                                     Wt0, b0, Wt1, b1, Wt2, b2, out, M);
    }
}

// Round 11
// 404.900 us; speedup vs baseline: 1.5099x; 1.3406x over previous
//
#include <hip/hip_runtime.h>

#define ACT_SHIFT (-4.5951198501345898f)   // log(1/(1-0.01) - 1)
#define DELTA 0.5f
#define XS 25600                            // 160*160
#define YS 160
#define NVOX 4096000

typedef __attribute__((ext_vector_type(8))) short short8;
typedef __attribute__((ext_vector_type(4))) float f32x4;
typedef __attribute__((ext_vector_type(2))) unsigned int u32x2;
typedef __attribute__((ext_vector_type(4))) unsigned int u32x4;

__device__ __forceinline__ float softplusf(float x) {
    return x > 20.f ? x : log1pf(expf(x));
}
__device__ __forceinline__ unsigned short f2b(float x) {        // RNE (prep paths)
    unsigned int u = __float_as_uint(x);
    u += 0x7fffu + ((u >> 16) & 1u);
    return (unsigned short)(u >> 16);
}
__device__ __forceinline__ unsigned short f2b_fast(float x) {   // round-half-up (verified r6)
    return (unsigned short)((__float_as_uint(x) + 0x8000u) >> 16);
}
__device__ __forceinline__ float blo(unsigned int u) { return __uint_as_float(u << 16); }
__device__ __forceinline__ float bhi(unsigned int u) { return __uint_as_float(u & 0xffff0000u); }

__device__ __forceinline__ void trisetup(float px, float py, float pz,
                                         int& ix, int& iy, int& iz,
                                         float& fx, float& fy, float& fz) {
    float sx = (px + 1.f) * 0.5f * 159.f;
    float sy = (py + 1.f) * 0.5f * 159.f;
    float sz = (pz + 1.f) * 0.5f * 159.f;
    sx = fminf(fmaxf(sx, 0.f), 159.f);
    sy = fminf(fmaxf(sy, 0.f), 159.f);
    sz = fminf(fmaxf(sz, 0.f), 159.f);
    ix = (int)sx; if (ix > 158) ix = 158;
    iy = (int)sy; if (iy > 158) iy = 158;
    iz = (int)sz; if (iz > 158) iz = 158;
    fx = sx - (float)ix;
    fy = sy - (float)iy;
    fz = sz - (float)iz;
}

// ================= grid builders =================
__global__ void k_t64(const float* __restrict__ k0, const float* __restrict__ dg,
                      unsigned int* __restrict__ grid) {
    int tid = blockIdx.x * 256 + threadIdx.x;
    if (tid >= NVOX) return;
    int z = tid % 160;
    int t1 = (z < 159) ? tid + 1 : tid;
    unsigned int w[16];
    #pragma unroll
    for (int j = 0; j < 6; j++) {
        w[j]   = (unsigned int)f2b(k0[(size_t)(2*j)*NVOX + tid]) | ((unsigned int)f2b(k0[(size_t)(2*j+1)*NVOX + tid]) << 16);
        w[6+j] = (unsigned int)f2b(k0[(size_t)(2*j)*NVOX + t1])  | ((unsigned int)f2b(k0[(size_t)(2*j+1)*NVOX + t1])  << 16);
    }
    w[12] = __float_as_uint(dg[tid]);
    w[13] = __float_as_uint(dg[t1]);
    w[14] = 0u; w[15] = 0u;
    u32x4* dst = (u32x4*)(grid + (size_t)tid * 16);
    dst[0] = *(u32x4*)(w);  dst[1] = *(u32x4*)(w+4);
    dst[2] = *(u32x4*)(w+8); dst[3] = *(u32x4*)(w+12);
}

__global__ void k_t32(const float* __restrict__ k0, const float* __restrict__ dg,
                      unsigned int* __restrict__ grid) {
    int tid = blockIdx.x * 256 + threadIdx.x;
    if (tid >= NVOX) return;
    unsigned int w[8];
    #pragma unroll
    for (int j = 0; j < 6; j++)
        w[j] = (unsigned int)f2b(k0[(size_t)(2*j)*NVOX + tid]) | ((unsigned int)f2b(k0[(size_t)(2*j+1)*NVOX + tid]) << 16);
    w[6] = __float_as_uint(dg[tid]);
    w[7] = 0u;
    u32x4* dst = (u32x4*)(grid + (size_t)tid * 8);
    dst[0] = *(u32x4*)(w); dst[1] = *(u32x4*)(w+4);
}
__global__ void k_t24(const float* __restrict__ k0, unsigned int* __restrict__ grid) {
    int tid = blockIdx.x * 256 + threadIdx.x;
    if (tid >= NVOX) return;
    unsigned int o[6];
    #pragma unroll
    for (int j = 0; j < 6; j++)
        o[j] = (unsigned int)f2b(k0[(size_t)(2*j)*NVOX + tid]) | ((unsigned int)f2b(k0[(size_t)(2*j+1)*NVOX + tid]) << 16);
    unsigned int* dst = grid + (size_t)tid * 6;
    #pragma unroll
    for (int j = 0; j < 6; j++) dst[j] = o[j];
}

// ================= small prep kernels =================
// Feature order: slots 0..26 = vd_emb, 27 = pad0, 28..36 = k0 ch3..11, 37..63 = 0
__global__ void k_wprep(const float* __restrict__ W0, const float* __restrict__ W1,
                        const float* __restrict__ W2,
                        unsigned short* __restrict__ Wt0, unsigned short* __restrict__ Wt1,
                        unsigned short* __restrict__ Wt2) {
    int id = blockIdx.x * 256 + threadIdx.x;
    if (id < 128 * 64) {
        int n = id >> 6, k = id & 63;
        float v = 0.f;
        if (k < 27)                 v = W0[(9 + k) * 128 + n];
        else if (k >= 28 && k < 37) v = W0[(k - 28) * 128 + n];
        Wt0[id] = f2b(v);
    }
    if (id < 128 * 128) { int n = id >> 7, k = id & 127; Wt1[id] = f2b(W1[k*128 + n]); }
    if (id < 16 * 128)  { int n = id >> 7, k = id & 127; Wt2[id] = (n < 3) ? f2b(W2[k*3 + n]) : 0; }
}

__global__ void k_starts(const int* __restrict__ rid, int* __restrict__ starts, int M, int R) {
    int r = blockIdx.x * blockDim.x + threadIdx.x;
    if (r > R) return;
    int lo = 0, hi = M;
    while (lo < hi) { int mid = (lo + hi) >> 1; if (rid[mid] < r) lo = mid + 1; else hi = mid; }
    starts[r] = lo;
}

__global__ void k_vdemb(const float* __restrict__ vd, unsigned short* __restrict__ emb, int R) {
    int r = blockIdx.x * blockDim.x + threadIdx.x;
    if (r >= R) return;
    float e[28];
    float v0 = vd[3*r], v1 = vd[3*r+1], v2 = vd[3*r+2];
    e[0] = v0; e[1] = v1; e[2] = v2;
    float v[3] = {v0, v1, v2};
    #pragma unroll
    for (int d = 0; d < 3; d++) {
        #pragma unroll
        for (int p = 0; p < 4; p++) {
            float a = v[d] * (float)(1 << p);
            e[3 + d*4 + p]  = sinf(a);
            e[15 + d*4 + p] = cosf(a);
        }
    }
    e[27] = 0.f;
    unsigned short* o = emb + r * 28;
    #pragma unroll
    for (int j = 0; j < 28; j++) o[j] = f2b(e[j]);
}

__global__ void k_densityC(const float* __restrict__ dg, const float* __restrict__ xyz,
                           float2* __restrict__ alog, int M) {
    int i = blockIdx.x * blockDim.x + threadIdx.x;
    if (i >= M) return;
    int ix, iy, iz; float fx, fy, fz;
    trisetup(xyz[3*i], xyz[3*i+1], xyz[3*i+2], ix, iy, iz, fx, fy, fz);
    const float* g = dg + ix * XS + iy * YS + iz;
    float gx = 1.f - fx, gy = 1.f - fy, gz = 1.f - fz;
    float v =
        gx * (gy * (gz * g[0]      + fz * g[1])      + fy * (gz * g[YS]      + fz * g[YS+1])) +
        fx * (gy * (gz * g[XS]     + fz * g[XS+1])   + fy * (gz * g[XS+YS]   + fz * g[XS+YS+1]));
    float sp = softplusf(v + ACT_SHIFT);
    float l  = -sp * DELTA;
    alog[i] = make_float2(1.f - expf(l), fmaxf(l, -15.9424285f));
}

// ================= gather: 2 threads/point =================
// rec[i] (32B): w0=(c3,c4) w1=(c5,c6) w2=(c7,c8) w3=(c9,c10) w4=(c11,0) w5..7=diff f32
template<int VOX>
__global__ __launch_bounds__(256) void k_gather(
    const unsigned int* __restrict__ grid, const float* __restrict__ dg,
    const float* __restrict__ xyz,
    u32x4* __restrict__ rec, float2* __restrict__ alog, int M) {

    const int t = blockIdx.x * 256 + threadIdx.x;
    const int p = t >> 1;
    const int dx = t & 1;
    if (p >= M) return;
    const int i = p;

    int ix, iy, iz; float fx, fy, fz;
    trisetup(xyz[3*i], xyz[3*i+1], xyz[3*i+2], ix, iy, iz, fx, fy, fz);
    float gz = 1.f - fz;
    float wx = dx ? fx : (1.f - fx);
    float wy[2] = {wx * (1.f - fy), wx * fy};

    float ch[12];
    #pragma unroll
    for (int c = 0; c < 12; c++) ch[c] = 0.f;
    float dd = 0.f;
    const int x = ix + dx;

    #pragma unroll
    for (int dy = 0; dy < 2; dy++) {
        float wc = wy[dy];
        size_t idx = (size_t)(x * 160 + (iy + dy)) * 160 + iz;
        if (VOX == 64) {
            const u32x4* e = (const u32x4*)(grid + idx * 16);
            u32x4 q0 = e[0], q1 = e[1], q2 = e[2], q3 = e[3];
            unsigned int wz[6]  = {q0[0],q0[1],q0[2],q0[3],q1[0],q1[1]};
            unsigned int wz1[6] = {q1[2],q1[3],q2[0],q2[1],q2[2],q2[3]};
            #pragma unroll
            for (int j = 0; j < 6; j++) {
                ch[2*j]   += wc * (gz * blo(wz[j]) + fz * blo(wz1[j]));
                ch[2*j+1] += wc * (gz * bhi(wz[j]) + fz * bhi(wz1[j]));
            }
            dd += wc * (gz * __uint_as_float(q3[0]) + fz * __uint_as_float(q3[1]));
        } else if (VOX == 32) {
            const u32x4* e0 = (const u32x4*)(grid + idx * 8);
            const u32x4* e1 = (const u32x4*)(grid + (idx + 1) * 8);
            u32x4 a0 = e0[0], a1 = e0[1], b0 = e1[0], b1 = e1[1];
            unsigned int wz[6]  = {a0[0],a0[1],a0[2],a0[3],a1[0],a1[1]};
            unsigned int wz1[6] = {b0[0],b0[1],b0[2],b0[3],b1[0],b1[1]};
            #pragma unroll
            for (int j = 0; j < 6; j++) {
                ch[2*j]   += wc * (gz * blo(wz[j]) + fz * blo(wz1[j]));
                ch[2*j+1] += wc * (gz * bhi(wz[j]) + fz * bhi(wz1[j]));
            }
            dd += wc * (gz * __uint_as_float(a1[2]) + fz * __uint_as_float(b1[2]));
        } else {
            const u32x2* e = (const u32x2*)(grid + idx * 6);
            u32x2 a0 = e[0], a1 = e[1], a2 = e[2], a3 = e[3], a4 = e[4], a5 = e[5];
            unsigned int wz[6]  = {a0[0],a0[1],a1[0],a1[1],a2[0],a2[1]};
            unsigned int wz1[6] = {a3[0],a3[1],a4[0],a4[1],a5[0],a5[1]};
            #pragma unroll
            for (int j = 0; j < 6; j++) {
                ch[2*j]   += wc * (gz * blo(wz[j]) + fz * blo(wz1[j]));
                ch[2*j+1] += wc * (gz * bhi(wz[j]) + fz * bhi(wz1[j]));
            }
            const float* dr = dg + (size_t)(x * 160 + (iy + dy)) * 160 + iz;
            dd += wc * (gz * dr[0] + fz * dr[1]);
        }
    }

    #pragma unroll
    for (int c = 0; c < 12; c++) ch[c] += __shfl_xor(ch[c], 1);
    dd += __shfl_xor(dd, 1);

    if (dx == 0) {
        unsigned int w[8];
        w[0] = (unsigned int)f2b(ch[3]) | ((unsigned int)f2b(ch[4]) << 16);
        w[1] = (unsigned int)f2b(ch[5]) | ((unsigned int)f2b(ch[6]) << 16);
        w[2] = (unsigned int)f2b(ch[7]) | ((unsigned int)f2b(ch[8]) << 16);
        w[3] = (unsigned int)f2b(ch[9]) | ((unsigned int)f2b(ch[10]) << 16);
        w[4] = (unsigned int)f2b(ch[11]);
        w[5] = __float_as_uint(ch[0]);
        w[6] = __float_as_uint(ch[1]);
        w[7] = __float_as_uint(ch[2]);
        rec[(size_t)i*2]     = *(u32x4*)(w);
        rec[(size_t)i*2 + 1] = *(u32x4*)(w + 4);
    } else {
        float sp = softplusf(dd + ACT_SHIFT);
        float l  = -sp * DELTA;
        alog[i] = make_float2(1.f - expf(l), fmaxf(l, -15.9424285f));
    }
}

// ================= wave-per-ray scan =================
__global__ void k_scanw(const float2* __restrict__ alog, const int* __restrict__ starts,
                        float* __restrict__ wts, float* __restrict__ out, int R) {
    const int r = (blockIdx.x * blockDim.x + threadIdx.x) >> 6;
    const int lane = threadIdx.x & 63;
    if (r >= R) return;
    const int s = starts[r], e = starts[r + 1];
    float carry = 0.f;
    for (int i0 = s; i0 < e; i0 += 64) {
        int idx = i0 + lane;
        bool pr = idx < e;
        float a = 0.f, x = 0.f;
        if (pr) { float2 v = alog[idx]; a = v.x; x = v.y; }
        float incl = x;
        #pragma unroll
        for (int d = 1; d < 64; d <<= 1) {
            float tv = __shfl_up(incl, d);
            if (lane >= d) incl += tv;
        }
        if (pr) wts[idx] = a * expf(carry + (incl - x));
        carry += __shfl(incl, 63);
    }
    float ainv = expf(carry);
    if (lane == 0) { out[3*r] = ainv; out[3*r+1] = ainv; out[3*r+2] = ainv; }
}

// ================= MFMA MLP v6: v5 structure, relaxed reg cap + hoisted store bases ===
// feat in hL[0,16KB) (rows 0-127 x 128B, XOR swz). h rows 64-127 live at [16KB,32KB):
// NO aliasing with feat. Store addr = sb[ntl][v] + row_block*4096 (XOR is mt-invariant).
__global__ __launch_bounds__(256, 3) void k_mlp_s(
    const u32x4* __restrict__ rec, const int* __restrict__ rid,
    const unsigned short* __restrict__ vemb, const float* __restrict__ wts,
    const unsigned short* __restrict__ Wt0, const float* __restrict__ b0,
    const unsigned short* __restrict__ Wt1, const float* __restrict__ b1,
    const unsigned short* __restrict__ Wt2, const float* __restrict__ b2,
    float* __restrict__ out, int M) {

    __shared__ char hL[128 * 256];     // 32 KB; feat aliased into first 16 KB
    __shared__ float diffL[128 * 3];
    __shared__ float wgtL[128];
    __shared__ int   ridL[128];

    const int t = threadIdx.x;
    const int base = blockIdx.x * 128;

    // ---- staging: feat rows into hL[0..16KB) (row-major, swizzled) ----
    if (t < 128) {
        const int i = base + t;
        unsigned int fr[32];
        #pragma unroll
        for (int j = 19; j < 32; j++) fr[j] = 0u;
        float wpt = 0.f; int r = 0;
        float d0 = 0.f, d1 = 0.f, d2 = 0.f;
        if (i < M) {
            u32x4 r0 = rec[(size_t)i*2];
            u32x4 r1 = rec[(size_t)i*2 + 1];
            r = rid[i];
            wpt = wts[i];
            const unsigned int* vp = (const unsigned int*)(vemb + (size_t)r * 28);
            #pragma unroll
            for (int j = 0; j < 14; j++) fr[j] = vp[j];   // vemb (slot 27 pad=0)
            fr[14] = r0[0]; fr[15] = r0[1]; fr[16] = r0[2]; fr[17] = r0[3];
            fr[18] = r1[0] & 0xffffu;                      // (c11, 0)
            d0 = __uint_as_float(r1[1]); d1 = __uint_as_float(r1[2]); d2 = __uint_as_float(r1[3]);
        } else {
            #pragma unroll
            for (int j = 0; j < 19; j++) fr[j] = 0u;
        }
        diffL[t*3 + 0] = d0; diffL[t*3 + 1] = d1; diffL[t*3 + 2] = d2;
        wgtL[t] = wpt;
        ridL[t] = r;
        char* fp = hL + t * 128;
        unsigned int rs = (unsigned int)((t & 7) << 4);
        #pragma unroll
        for (int j = 0; j < 8; j++)
            *(u32x4*)(fp + ((16u*j) ^ rs)) = *(u32x4*)(fr + 4*j);
    }

    const int lane = t & 63;
    const int w = t >> 6;
    const int g = lane >> 4;
    const int ln = lane & 15;

    // hoisted h-store bases: addr(row=blk*16+4g+v, col=n0+ln) = sb[ntl][v] + blk*4096
    unsigned sb[2][4];
    #pragma unroll
    for (int ntl = 0; ntl < 2; ntl++) {
        const unsigned col2 = (unsigned)(((2*w + ntl)*16 + ln) * 2);
        #pragma unroll
        for (int v = 0; v < 4; v++) {
            const unsigned rsub = (unsigned)(4*g + v);
            sb[ntl][v] = ((rsub << 8) + col2) ^ ((rsub & 7u) << 4);
        }
    }

    // ---- hoist B1 ----
    short8 B1[2][2];
    float bias0[2];
    #pragma unroll
    for (int ntl = 0; ntl < 2; ntl++) {
        const int n0 = (2*w + ntl) * 16;
        const char* wb0 = (const char*)Wt0 + (n0 + ln) * 128 + 16*g;
        B1[ntl][0] = *(const short8*)(wb0);
        B1[ntl][1] = *(const short8*)(wb0 + 64);
        bias0[ntl] = b0[n0 + ln];
    }
    __syncthreads();   // feat staged

    // ---- L1 upper half (mt=4..7): compute + store immediately (no alias w/ feat) ----
    {
        f32x4 acc[4][2];
        #pragma unroll
        for (int mtl = 0; mtl < 4; mtl++) {
            const int arow = (4 + mtl)*16 + ln;
            const unsigned int aswz = (unsigned int)((arow & 7) << 4);
            const char* ab = hL + arow * 128;
            short8 a0 = *(const short8*)(ab + ((16u*g)        ^ aswz));
            short8 a1 = *(const short8*)(ab + ((64u + 16u*g)  ^ aswz));
            #pragma unroll
            for (int ntl = 0; ntl < 2; ntl++) {
                f32x4 a = {bias0[ntl], bias0[ntl], bias0[ntl], bias0[ntl]};
                a = __builtin_amdgcn_mfma_f32_16x16x32_bf16(a0, B1[ntl][0], a, 0, 0, 0);
                a = __builtin_amdgcn_mfma_f32_16x16x32_bf16(a1, B1[ntl][1], a, 0, 0, 0);
                acc[mtl][ntl] = a;
            }
        }
        #pragma unroll
        for (int mtl = 0; mtl < 4; mtl++) {
            #pragma unroll
            for (int ntl = 0; ntl < 2; ntl++) {
                #pragma unroll
                for (int v = 0; v < 4; v++) {
                    unsigned short hv = f2b_fast(fmaxf(acc[mtl][ntl][v], 0.f));
                    *(unsigned short*)(hL + sb[ntl][v] + 16384u + (unsigned)(mtl*4096)) = hv;
                }
            }
        }
    }

    // ---- L1 lower half (mt=0..3): compute into regs; store after barrier ----
    f32x4 accL[4][2];
    #pragma unroll
    for (int mtl = 0; mtl < 4; mtl++) {
        const int arow = mtl*16 + ln;
        const unsigned int aswz = (unsigned int)((arow & 7) << 4);
        const char* ab = hL + arow * 128;
        short8 a0 = *(const short8*)(ab + ((16u*g)        ^ aswz));
        short8 a1 = *(const short8*)(ab + ((64u + 16u*g)  ^ aswz));
        #pragma unroll
        for (int ntl = 0; ntl < 2; ntl++) {
            f32x4 a = {bias0[ntl], bias0[ntl], bias0[ntl], bias0[ntl]};
            a = __builtin_amdgcn_mfma_f32_16x16x32_bf16(a0, B1[ntl][0], a, 0, 0, 0);
            a = __builtin_amdgcn_mfma_f32_16x16x32_bf16(a1, B1[ntl][1], a, 0, 0, 0);
            accL[mtl][ntl] = a;
        }
    }
    // hoist B2 in the shadow
    short8 B2[2][4];
    float bias1[2];
    #pragma unroll
    for (int ntl = 0; ntl < 2; ntl++) {
        const int n0 = (2*w + ntl) * 16;
        const char* wb1 = (const char*)Wt1 + (n0 + ln) * 256 + 16*g;
        #pragma unroll
        for (int kk = 0; kk < 4; kk++)
            B2[ntl][kk] = *(const short8*)(wb1 + 64*kk);
        bias1[ntl] = b1[n0 + ln];
    }
    __syncthreads();   // all feat reads done -> safe to overwrite feat region
    #pragma unroll
    for (int mtl = 0; mtl < 4; mtl++) {
        #pragma unroll
        for (int ntl = 0; ntl < 2; ntl++) {
            #pragma unroll
            for (int v = 0; v < 4; v++) {
                unsigned short hv = f2b_fast(fmaxf(accL[mtl][ntl][v], 0.f));
                *(unsigned short*)(hL + sb[ntl][v] + (unsigned)(mtl*4096)) = hv;
            }
        }
    }
    __syncthreads();   // h1 fully visible

    // ---- L2 half A (mt=0..3): read rows 0..63, barrier, store h2 rows 0..63 ----
    {
        f32x4 acc[4][2];
        #pragma unroll
        for (int mtl = 0; mtl < 4; mtl++) {
            const int arow = mtl*16 + ln;
            const unsigned int aswz = (unsigned int)((arow & 7) << 4);
            const char* ab = hL + arow * 256;
            short8 a0 = *(const short8*)(ab + ((16u*g)         ^ aswz));
            short8 a1 = *(const short8*)(ab + ((64u  + 16u*g)  ^ aswz));
            short8 a2 = *(const short8*)(ab + ((128u + 16u*g)  ^ aswz));
            short8 a3 = *(const short8*)(ab + ((192u + 16u*g)  ^ aswz));
            #pragma unroll
            for (int ntl = 0; ntl < 2; ntl++) {
                f32x4 a = {bias1[ntl], bias1[ntl], bias1[ntl], bias1[ntl]};
                a = __builtin_amdgcn_mfma_f32_16x16x32_bf16(a0, B2[ntl][0], a, 0, 0, 0);
                a = __builtin_amdgcn_mfma_f32_16x16x32_bf16(a1, B2[ntl][1], a, 0, 0, 0);
                a = __builtin_amdgcn_mfma_f32_16x16x32_bf16(a2, B2[ntl][2], a, 0, 0, 0);
                a = __builtin_amdgcn_mfma_f32_16x16x32_bf16(a3, B2[ntl][3], a, 0, 0, 0);
                acc[mtl][ntl] = a;
            }
        }
        __syncthreads();   // all reads of rows 0..63 done
        #pragma unroll
        for (int mtl = 0; mtl < 4; mtl++) {
            #pragma unroll
            for (int ntl = 0; ntl < 2; ntl++) {
                #pragma unroll
                for (int v = 0; v < 4; v++) {
                    unsigned short hv = f2b_fast(fmaxf(acc[mtl][ntl][v], 0.f));
                    *(unsigned short*)(hL + sb[ntl][v] + (unsigned)(mtl*4096)) = hv;
                }
            }
        }
    }

    // ---- L2 half B (mt=4..7): reads rows 64..127 (disjoint from half-A stores) ----
    {
        f32x4 acc[4][2];
        #pragma unroll
        for (int mtl = 0; mtl < 4; mtl++) {
            const int arow = (4 + mtl)*16 + ln;
            const unsigned int aswz = (unsigned int)((arow & 7) << 4);
            const char* ab = hL + arow * 256;
            short8 a0 = *(const short8*)(ab + ((16u*g)         ^ aswz));
            short8 a1 = *(const short8*)(ab + ((64u  + 16u*g)  ^ aswz));
            short8 a2 = *(const short8*)(ab + ((128u + 16u*g)  ^ aswz));
            short8 a3 = *(const short8*)(ab + ((192u + 16u*g)  ^ aswz));
            #pragma unroll
            for (int ntl = 0; ntl < 2; ntl++) {
                f32x4 a = {bias1[ntl], bias1[ntl], bias1[ntl], bias1[ntl]};
                a = __builtin_amdgcn_mfma_f32_16x16x32_bf16(a0, B2[ntl][0], a, 0, 0, 0);
                a = __builtin_amdgcn_mfma_f32_16x16x32_bf16(a1, B2[ntl][1], a, 0, 0, 0);
                a = __builtin_amdgcn_mfma_f32_16x16x32_bf16(a2, B2[ntl][2], a, 0, 0, 0);
                a = __builtin_amdgcn_mfma_f32_16x16x32_bf16(a3, B2[ntl][3], a, 0, 0, 0);
                acc[mtl][ntl] = a;
            }
        }
        __syncthreads();   // all reads of rows 64..127 done
        #pragma unroll
        for (int mtl = 0; mtl < 4; mtl++) {
            #pragma unroll
            for (int ntl = 0; ntl < 2; ntl++) {
                #pragma unroll
                for (int v = 0; v < 4; v++) {
                    unsigned short hv = f2b_fast(fmaxf(acc[mtl][ntl][v], 0.f));
                    *(unsigned short*)(hL + sb[ntl][v] + 16384u + (unsigned)(mtl*4096)) = hv;
                }
            }
        }
    }

    // hoist B3 in the barrier shadow
    short8 B3[4];
    {
        const char* wb2 = (const char*)Wt2 + ln * 256 + 16*g;
        #pragma unroll
        for (int kk = 0; kk < 4; kk++) B3[kk] = *(const short8*)(wb2 + 64*kk);
    }
    __syncthreads();   // h2 complete

    // ---- layer 3 (M-split: rows 32w..32w+31) + sigmoid + ray-merged atomics ----
    {
        const float b2c = (ln < 3) ? b2[ln] : 0.f;
        #pragma unroll
        for (int mi = 0; mi < 2; mi++) {
            const int m0 = 32*w + 16*mi;
            const int arow = m0 + ln;
            const unsigned int aswz = (unsigned int)((arow & 7) << 4);
            const char* ab = hL + arow * 256;
            short8 a0 = *(const short8*)(ab + ((16u*g)         ^ aswz));
            short8 a1 = *(const short8*)(ab + ((64u  + 16u*g)  ^ aswz));
            short8 a2 = *(const short8*)(ab + ((128u + 16u*g)  ^ aswz));
            short8 a3 = *(const short8*)(ab + ((192u + 16u*g)  ^ aswz));
            f32x4 acc = {0.f, 0.f, 0.f, 0.f};
            acc = __builtin_amdgcn_mfma_f32_16x16x32_bf16(a0, B3[0], acc, 0, 0, 0);
            acc = __builtin_amdgcn_mfma_f32_16x16x32_bf16(a1, B3[1], acc, 0, 0, 0);
            acc = __builtin_amdgcn_mfma_f32_16x16x32_bf16(a2, B3[2], acc, 0, 0, 0);
            acc = __builtin_amdgcn_mfma_f32_16x16x32_bf16(a3, B3[3], acc, 0, 0, 0);

            float val[4];
            #pragma unroll
            for (int v = 0; v < 4; v++) {
                int row = m0 + 4*g + v;
                float logit = acc[v] + b2c + diffL[row*3 + ln];
                val[v] = (ln < 3) ? wgtL[row] / (1.f + expf(-logit)) : 0.f;
            }
            int r0t = ridL[m0], r15t = ridL[m0 + 15];
            if (r0t == r15t) {
                float s = val[0] + val[1] + val[2] + val[3];
                s += __shfl_xor(s, 16);
                s += __shfl_xor(s, 32);
                if (g == 0 && ln < 3) atomicAdd(out + 3*r0t + ln, s);
            } else if (ln < 3) {
                int rr = ridL[m0 + 4*g];
                float run = val[0];
                #pragma unroll
                for (int v = 1; v < 4; v++) {
                    int rv = ridL[m0 + 4*g + v];
                    if (rv == rr) run += val[v];
                    else { atomicAdd(out + 3*rr + ln, run); run = val[v]; rr = rv; }
                }
                atomicAdd(out + 3*rr + ln, run);
            }
        }
    }
}

// ================= legacy fused MLP (ultra fallback, 24B grid) =================
__global__ __launch_bounds__(256) void k_mlp_fused(
    const unsigned short* __restrict__ k0b, const float* __restrict__ xyz,
    const int* __restrict__ rid, const unsigned short* __restrict__ vemb,
    const float* __restrict__ wts,
    const unsigned short* __restrict__ Wt0, const float* __restrict__ b0,
    const unsigned short* __restrict__ Wt1, const float* __restrict__ b1,
    const unsigned short* __restrict__ Wt2, const float* __restrict__ b2,
    float* __restrict__ out, int M) {

    __shared__ char featL[128 * 128];
    __shared__ char hL[128 * 256];
    __shared__ float diffL[128 * 3];
    __shared__ float wgtL[128];
    __shared__ int   ridL[128];

    const int t = threadIdx.x;
    const int base = blockIdx.x * 128;
    const int p = t >> 1;
    const int dx = t & 1;
    const int i = base + p;

    float ch[12];
    #pragma unroll
    for (int c = 0; c < 12; c++) ch[c] = 0.f;

    if (i < M) {
        int ix, iy, iz; float fx, fy, fz;
        trisetup(xyz[3*i], xyz[3*i+1], xyz[3*i+2], ix, iy, iz, fx, fy, fz);
        float gz = 1.f - fz;
        float wx = dx ? fx : (1.f - fx);
        float wy0 = wx * (1.f - fy), wy1 = wx * fy;
        #pragma unroll
        for (int dy = 0; dy < 2; dy++) {
            float w2 = dy ? wy1 : wy0;
            size_t vox = (size_t)((ix + dx) * 160 + (iy + dy)) * 160 + iz;
            const char* pv = (const char*)k0b + vox * 24;
            u32x2 a0 = *(const u32x2*)(pv);
            u32x2 a1 = *(const u32x2*)(pv + 8);
            u32x2 a2 = *(const u32x2*)(pv + 16);
            u32x2 a3 = *(const u32x2*)(pv + 24);
            u32x2 a4 = *(const u32x2*)(pv + 32);
            u32x2 a5 = *(const u32x2*)(pv + 40);
            unsigned int u0[6] = {a0[0],a0[1],a1[0],a1[1],a2[0],a2[1]};
            unsigned int u1[6] = {a3[0],a3[1],a4[0],a4[1],a5[0],a5[1]};
            #pragma unroll
            for (int j = 0; j < 6; j++) {
                ch[2*j]   += w2 * (gz * blo(u0[j]) + fz * blo(u1[j]));
                ch[2*j+1] += w2 * (gz * bhi(u0[j]) + fz * bhi(u1[j]));
            }
        }
    }
    #pragma unroll
    for (int c = 0; c < 12; c++) ch[c] += __shfl_xor(ch[c], 1);

    if (dx == 0) {
        unsigned int fr[32];
        #pragma unroll
        for (int j = 19; j < 32; j++) fr[j] = 0u;
        float wpt = 0.f; int r = 0;
        if (i < M) {
            r = rid[i];
            wpt = wts[i];
            const unsigned int* vp = (const unsigned int*)(vemb + (size_t)r * 28);
            #pragma unroll
            for (int j = 0; j < 14; j++) fr[j] = vp[j];
            fr[14] = (unsigned int)f2b(ch[3]) | ((unsigned int)f2b(ch[4]) << 16);
            fr[15] = (unsigned int)f2b(ch[5]) | ((unsigned int)f2b(ch[6]) << 16);
            fr[16] = (unsigned int)f2b(ch[7]) | ((unsigned int)f2b(ch[8]) << 16);
            fr[17] = (unsigned int)f2b(ch[9]) | ((unsigned int)f2b(ch[10]) << 16);
            fr[18] = (unsigned int)f2b(ch[11]);
        } else {
            #pragma unroll
            for (int j = 0; j < 19; j++) fr[j] = 0u;
        }
        diffL[p*3 + 0] = ch[0];
        diffL[p*3 + 1] = ch[1];
        diffL[p*3 + 2] = ch[2];
        wgtL[p] = wpt;
        ridL[p] = r;
        char* fp = featL + p * 128;
        unsigned int rs = (unsigned int)((p & 7) << 4);
        #pragma unroll
        for (int j = 0; j < 8; j++)
            *(u32x4*)(fp + ((16u*j) ^ rs)) = *(u32x4*)(fr + 4*j);
    }
    __syncthreads();

    const int lane = t & 63;
    const int w = t >> 6;
    const int g = lane >> 4;
    const int ln = lane & 15;

    #pragma unroll
    for (int mi = 0; mi < 2; mi++) {
        const int m0 = 32*w + 16*mi;
        const int arow = m0 + ln;
        const unsigned int aswz = (unsigned int)((arow & 7) << 4);
        const char* ab = featL + arow * 128;
        short8 a0 = *(const short8*)(ab + ((16u*g)        ^ aswz));
        short8 a1 = *(const short8*)(ab + ((64u + 16u*g)  ^ aswz));
        #pragma unroll
        for (int nt = 0; nt < 8; nt++) {
            const int n0 = 16 * nt;
            float bias = b0[n0 + ln];
            f32x4 acc = {bias, bias, bias, bias};
            const char* wb = (const char*)Wt0 + (n0 + ln) * 128;
            acc = __builtin_amdgcn_mfma_f32_16x16x32_bf16(a0, *(const short8*)(wb + 16*g),      acc, 0, 0, 0);
            acc = __builtin_amdgcn_mfma_f32_16x16x32_bf16(a1, *(const short8*)(wb + 64 + 16*g), acc, 0, 0, 0);
            #pragma unroll
            for (int v = 0; v < 4; v++) {
                int row = m0 + 4*g + v;
                unsigned short hv = f2b_fast(fmaxf(acc[v], 0.f));
                *(unsigned short*)(hL + (((unsigned)(row*256 + (n0+ln)*2)) ^ ((unsigned)((row & 7) << 4)))) = hv;
            }
        }
    }

    #pragma unroll
    for (int mi = 0; mi < 2; mi++) {
        const int m0 = 32*w + 16*mi;
        const int arow = m0 + ln;
        const unsigned int aswz = (unsigned int)((arow & 7) << 4);
        const char* ab = hL + arow * 256;
        short8 a0 = *(const short8*)(ab + ((16u*g)         ^ aswz));
        short8 a1 = *(const short8*)(ab + ((64u  + 16u*g)  ^ aswz));
        short8 a2 = *(const short8*)(ab + ((128u + 16u*g)  ^ aswz));
        short8 a3 = *(const short8*)(ab + ((192u + 16u*g)  ^ aswz));
        #pragma unroll
        for (int nt = 0; nt < 8; nt++) {
            const int n0 = 16 * nt;
            float bias = b1[n0 + ln];
            f32x4 acc = {bias, bias, bias, bias};
            const char* wb = (const char*)Wt1 + (n0 + ln) * 256;
            acc = __builtin_amdgcn_mfma_f32_16x16x32_bf16(a0, *(const short8*)(wb + 16*g),       acc, 0, 0, 0);
            acc = __builtin_amdgcn_mfma_f32_16x16x32_bf16(a1, *(const short8*)(wb + 64 + 16*g),  acc, 0, 0, 0);
            acc = __builtin_amdgcn_mfma_f32_16x16x32_bf16(a2, *(const short8*)(wb + 128 + 16*g), acc, 0, 0, 0);
            acc = __builtin_amdgcn_mfma_f32_16x16x32_bf16(a3, *(const short8*)(wb + 192 + 16*g), acc, 0, 0, 0);
            #pragma unroll
            for (int v = 0; v < 4; v++) {
                int row = m0 + 4*g + v;
                unsigned short hv = f2b_fast(fmaxf(acc[v], 0.f));
                *(unsigned short*)(hL + (((unsigned)(row*256 + (n0+ln)*2)) ^ ((unsigned)((row & 7) << 4)))) = hv;
            }
        }
    }

    const float b2c = (ln < 3) ? b2[ln] : 0.f;
    #pragma unroll
    for (int mi = 0; mi < 2; mi++) {
        const int m0 = 32*w + 16*mi;
        const int arow = m0 + ln;
        const unsigned int aswz = (unsigned int)((arow & 7) << 4);
        const char* ab = hL + arow * 256;
        short8 a0 = *(const short8*)(ab + ((16u*g)         ^ aswz));
        short8 a1 = *(const short8*)(ab + ((64u  + 16u*g)  ^ aswz));
        short8 a2 = *(const short8*)(ab + ((128u + 16u*g)  ^ aswz));
        short8 a3 = *(const short8*)(ab + ((192u + 16u*g)  ^ aswz));
        f32x4 acc = {0.f, 0.f, 0.f, 0.f};
        const char* wb = (const char*)Wt2 + ln * 256;
        acc = __builtin_amdgcn_mfma_f32_16x16x32_bf16(a0, *(const short8*)(wb + 16*g),       acc, 0, 0, 0);
        acc = __builtin_amdgcn_mfma_f32_16x16x32_bf16(a1, *(const short8*)(wb + 64 + 16*g),  acc, 0, 0, 0);
        acc = __builtin_amdgcn_mfma_f32_16x16x32_bf16(a2, *(const short8*)(wb + 128 + 16*g), acc, 0, 0, 0);
        acc = __builtin_amdgcn_mfma_f32_16x16x32_bf16(a3, *(const short8*)(wb + 192 + 16*g), acc, 0, 0, 0);

        float val[4];
        #pragma unroll
        for (int v = 0; v < 4; v++) {
            int row = m0 + 4*g + v;
            float logit = acc[v] + b2c + diffL[row*3 + ln];
            val[v] = (ln < 3) ? wgtL[row] / (1.f + expf(-logit)) : 0.f;
        }
        int r0t = ridL[m0], r15t = ridL[m0 + 15];
        if (r0t == r15t) {
            float s = val[0] + val[1] + val[2] + val[3];
            s += __shfl_xor(s, 16);
            s += __shfl_xor(s, 32);
            if (g == 0 && ln < 3) atomicAdd(out + 3*r0t + ln, s);
        } else if (ln < 3) {
            int rr = ridL[m0 + 4*g];
            float run = val[0];
            #pragma unroll
            for (int v = 1; v < 4; v++) {
                int rv = ridL[m0 + 4*g + v];
                if (rv == rr) run += val[v];
                else { atomicAdd(out + 3*rr + ln, run); run = val[v]; rr = rv; }
            }
            atomicAdd(out + 3*rr + ln, run);
        }
    }
}

extern "C" void kernel_launch(void* const* d_in, const int* in_sizes, int n_in,
                              void* d_out, int out_size, void* d_ws, size_t ws_size,
                              hipStream_t stream) {
    const float* dg  = (const float*)d_in[0];
    const float* k0  = (const float*)d_in[1];
    const float* xyz = (const float*)d_in[2];
    const float* vd  = (const float*)d_in[3];
    const float* W0  = (const float*)d_in[4];
    const float* b0  = (const float*)d_in[5];
    const float* W1  = (const float*)d_in[6];
    const float* b1  = (const float*)d_in[7];
    const float* W2  = (const float*)d_in[8];
    const float* b2  = (const float*)d_in[9];
    const int*   rid = (const int*)d_in[10];
    float* out = (float*)d_out;

    const int M = in_sizes[2] / 3;
    const int R = in_sizes[3] / 3;

    const size_t wtb    = (size_t)(128*64 + 128*128 + 16*128) * 2;
    const size_t vembsz = (size_t)R * 28 * 2;
    const size_t alogsz = (size_t)M * 8;
    const size_t wtssz  = (size_t)M * 4;
    const size_t stsz   = (size_t)(R + 1) * 4;
    const size_t recsz  = (size_t)M * 32;
    const size_t fixed  = wtb + vembsz + alogsz + wtssz + stsz + 1024;

    const size_t need64 = (size_t)NVOX * 64 + fixed + recsz;
    const size_t need32 = (size_t)NVOX * 32 + fixed + recsz;
    const size_t need24 = (size_t)NVOX * 24 + fixed + recsz;

    int tier = (ws_size >= need64) ? 64 : (ws_size >= need32) ? 32 :
               (ws_size >= need24) ? 24 : 0;
    const size_t gridb = (tier == 64) ? (size_t)NVOX*64 : (tier == 32) ? (size_t)NVOX*32 : (size_t)NVOX*24;

    char* w = (char*)d_ws;
    unsigned int*   gridp = (unsigned int*)w;   w += gridb;
    unsigned short* Wt0   = (unsigned short*)w; w += 128*64*2;
    unsigned short* Wt1   = (unsigned short*)w; w += 128*128*2;
    unsigned short* Wt2   = (unsigned short*)w; w += 16*128*2;
    unsigned short* vembb = (unsigned short*)w; w += vembsz;
    float2* alog  = (float2*)w;  w += alogsz;
    float*  wts   = (float*)w;   w += wtssz;
    int*    starts= (int*)w;     w += stsz;
    w = (char*)(((size_t)w + 255) & ~(size_t)255);
    u32x4*  rec   = (u32x4*)w;

    const int gb = (NVOX + 255) / 256;
    k_wprep <<<dim3(64), dim3(256), 0, stream>>>(W0, W1, W2, Wt0, Wt1, Wt2);
    k_starts<<<dim3((R + 256) / 256), dim3(256), 0, stream>>>(rid, starts, M, R);
    k_vdemb <<<dim3((R + 255) / 256), dim3(256), 0, stream>>>(vd, vembb, R);

    if (tier > 0) {
        if (tier == 64)      k_t64<<<dim3(gb), dim3(256), 0, stream>>>(k0, dg, gridp);
        else if (tier == 32) k_t32<<<dim3(gb), dim3(256), 0, stream>>>(k0, dg, gridp);
        else                 k_t24<<<dim3(gb), dim3(256), 0, stream>>>(k0, gridp);

        const int gblocks = (2 * M + 255) / 256;
        if (tier == 64)
            k_gather<64><<<dim3(gblocks), dim3(256), 0, stream>>>(gridp, dg, xyz, rec, alog, M);
        else if (tier == 32)
            k_gather<32><<<dim3(gblocks), dim3(256), 0, stream>>>(gridp, dg, xyz, rec, alog, M);
        else
            k_gather<24><<<dim3(gblocks), dim3(256), 0, stream>>>(gridp, dg, xyz, rec, alog, M);

        k_scanw<<<dim3(((size_t)R * 64 + 255) / 256), dim3(256), 0, stream>>>(alog, starts, wts, out, R);
        k_mlp_s<<<dim3((M + 127) / 128), dim3(256), 0, stream>>>(rec, rid, vembb, wts,
                                                                 Wt0, b0, Wt1, b1, Wt2, b2, out, M);
    } else {
        k_t24    <<<dim3(gb), dim3(256), 0, stream>>>(k0, gridp);
        k_densityC<<<dim3((M + 255) / 256), dim3(256), 0, stream>>>(dg, xyz, alog, M);
        k_scanw  <<<dim3(((size_t)R * 64 + 255) / 256), dim3(256), 0, stream>>>(alog, starts, wts, out, R);
        k_mlp_fused<<<dim3((M + 127) / 128), dim3(256), 0, stream>>>((const unsigned short*)gridp, xyz, rid, vembb, wts,
                                                                     Wt0, b0, Wt1, b1, Wt2, b2, out, M);
    }
}

// Round 12
// 398.477 us; speedup vs baseline: 1.5342x; 1.0161x over previous
//
#include <hip/hip_runtime.h>

#define ACT_SHIFT (-4.5951198501345898f)   // log(1/(1-0.01) - 1)
#define DELTA 0.5f
#define XS 25600                            // 160*160
#define YS 160
#define NVOX 4096000

typedef __attribute__((ext_vector_type(8))) short short8;
typedef __attribute__((ext_vector_type(4))) float f32x4;
typedef __attribute__((ext_vector_type(2))) unsigned int u32x2;
typedef __attribute__((ext_vector_type(4))) unsigned int u32x4;

__device__ __forceinline__ float softplusf(float x) {
    return x > 20.f ? x : log1pf(expf(x));
}
__device__ __forceinline__ unsigned short f2b(float x) {        // RNE (prep paths)
    unsigned int u = __float_as_uint(x);
    u += 0x7fffu + ((u >> 16) & 1u);
    return (unsigned short)(u >> 16);
}
__device__ __forceinline__ unsigned short f2b_fast(float x) {   // round-half-up (verified r6)
    return (unsigned short)((__float_as_uint(x) + 0x8000u) >> 16);
}
__device__ __forceinline__ float blo(unsigned int u) { return __uint_as_float(u << 16); }
__device__ __forceinline__ float bhi(unsigned int u) { return __uint_as_float(u & 0xffff0000u); }

__device__ __forceinline__ void trisetup(float px, float py, float pz,
                                         int& ix, int& iy, int& iz,
                                         float& fx, float& fy, float& fz) {
    float sx = (px + 1.f) * 0.5f * 159.f;
    float sy = (py + 1.f) * 0.5f * 159.f;
    float sz = (pz + 1.f) * 0.5f * 159.f;
    sx = fminf(fmaxf(sx, 0.f), 159.f);
    sy = fminf(fmaxf(sy, 0.f), 159.f);
    sz = fminf(fmaxf(sz, 0.f), 159.f);
    ix = (int)sx; if (ix > 158) ix = 158;
    iy = (int)sy; if (iy > 158) iy = 158;
    iz = (int)sz; if (iz > 158) iz = 158;
    fx = sx - (float)ix;
    fy = sy - (float)iy;
    fz = sz - (float)iz;
}

// ================= grid builders =================
// VOX32: entry(x,y,z) = {ch0..11(z) bf16 (24B), d(z) f32, pad}  -> 131 MB, L3-resident
__global__ void k_t32(const float* __restrict__ k0, const float* __restrict__ dg,
                      unsigned int* __restrict__ grid) {
    int tid = blockIdx.x * 256 + threadIdx.x;
    if (tid >= NVOX) return;
    unsigned int w[8];
    #pragma unroll
    for (int j = 0; j < 6; j++)
        w[j] = (unsigned int)f2b(k0[(size_t)(2*j)*NVOX + tid]) | ((unsigned int)f2b(k0[(size_t)(2*j+1)*NVOX + tid]) << 16);
    w[6] = __float_as_uint(dg[tid]);
    w[7] = 0u;
    u32x4* dst = (u32x4*)(grid + (size_t)tid * 8);
    dst[0] = *(u32x4*)(w); dst[1] = *(u32x4*)(w+4);
}
// VOX24 fallback (no density)
__global__ void k_t24(const float* __restrict__ k0, unsigned int* __restrict__ grid) {
    int tid = blockIdx.x * 256 + threadIdx.x;
    if (tid >= NVOX) return;
    unsigned int o[6];
    #pragma unroll
    for (int j = 0; j < 6; j++)
        o[j] = (unsigned int)f2b(k0[(size_t)(2*j)*NVOX + tid]) | ((unsigned int)f2b(k0[(size_t)(2*j+1)*NVOX + tid]) << 16);
    unsigned int* dst = grid + (size_t)tid * 6;
    #pragma unroll
    for (int j = 0; j < 6; j++) dst[j] = o[j];
}

// ================= small prep kernels =================
// Feature order: slots 0..26 = vd_emb, 27 = pad0, 28..36 = k0 ch3..11, 37..63 = 0
__global__ void k_wprep(const float* __restrict__ W0, const float* __restrict__ W1,
                        const float* __restrict__ W2,
                        unsigned short* __restrict__ Wt0, unsigned short* __restrict__ Wt1,
                        unsigned short* __restrict__ Wt2) {
    int id = blockIdx.x * 256 + threadIdx.x;
    if (id < 128 * 64) {
        int n = id >> 6, k = id & 63;
        float v = 0.f;
        if (k < 27)                 v = W0[(9 + k) * 128 + n];
        else if (k >= 28 && k < 37) v = W0[(k - 28) * 128 + n];
        Wt0[id] = f2b(v);
    }
    if (id < 128 * 128) { int n = id >> 7, k = id & 127; Wt1[id] = f2b(W1[k*128 + n]); }
    if (id < 16 * 128)  { int n = id >> 7, k = id & 127; Wt2[id] = (n < 3) ? f2b(W2[k*3 + n]) : 0; }
}

__global__ void k_starts(const int* __restrict__ rid, int* __restrict__ starts, int M, int R) {
    int r = blockIdx.x * blockDim.x + threadIdx.x;
    if (r > R) return;
    int lo = 0, hi = M;
    while (lo < hi) { int mid = (lo + hi) >> 1; if (rid[mid] < r) lo = mid + 1; else hi = mid; }
    starts[r] = lo;
}

__global__ void k_vdemb(const float* __restrict__ vd, unsigned short* __restrict__ emb, int R) {
    int r = blockIdx.x * blockDim.x + threadIdx.x;
    if (r >= R) return;
    float e[28];
    float v0 = vd[3*r], v1 = vd[3*r+1], v2 = vd[3*r+2];
    e[0] = v0; e[1] = v1; e[2] = v2;
    float v[3] = {v0, v1, v2};
    #pragma unroll
    for (int d = 0; d < 3; d++) {
        #pragma unroll
        for (int p = 0; p < 4; p++) {
            float a = v[d] * (float)(1 << p);
            e[3 + d*4 + p]  = sinf(a);
            e[15 + d*4 + p] = cosf(a);
        }
    }
    e[27] = 0.f;
    unsigned short* o = emb + r * 28;
    #pragma unroll
    for (int j = 0; j < 28; j++) o[j] = f2b(e[j]);
}

__global__ void k_densityC(const float* __restrict__ dg, const float* __restrict__ xyz,
                           float2* __restrict__ alog, int M) {
    int i = blockIdx.x * blockDim.x + threadIdx.x;
    if (i >= M) return;
    int ix, iy, iz; float fx, fy, fz;
    trisetup(xyz[3*i], xyz[3*i+1], xyz[3*i+2], ix, iy, iz, fx, fy, fz);
    const float* g = dg + ix * XS + iy * YS + iz;
    float gx = 1.f - fx, gy = 1.f - fy, gz = 1.f - fz;
    float v =
        gx * (gy * (gz * g[0]      + fz * g[1])      + fy * (gz * g[YS]      + fz * g[YS+1])) +
        fx * (gy * (gz * g[XS]     + fz * g[XS+1])   + fy * (gz * g[XS+YS]   + fz * g[XS+YS+1]));
    float sp = softplusf(v + ACT_SHIFT);
    float l  = -sp * DELTA;
    alog[i] = make_float2(1.f - expf(l), fmaxf(l, -15.9424285f));
}

// ================= gather: 2 threads/point =================
// rec[i] (32B): w0=(c3,c4) w1=(c5,c6) w2=(c7,c8) w3=(c9,c10) w4=(c11,0) w5..7=diff f32
template<int VOX>
__global__ __launch_bounds__(256) void k_gather(
    const unsigned int* __restrict__ grid, const float* __restrict__ dg,
    const float* __restrict__ xyz,
    u32x4* __restrict__ rec, float2* __restrict__ alog, int M) {

    const int t = blockIdx.x * 256 + threadIdx.x;
    const int p = t >> 1;
    const int dx = t & 1;
    if (p >= M) return;
    const int i = p;

    int ix, iy, iz; float fx, fy, fz;
    trisetup(xyz[3*i], xyz[3*i+1], xyz[3*i+2], ix, iy, iz, fx, fy, fz);
    float gz = 1.f - fz;
    float wx = dx ? fx : (1.f - fx);
    float wy[2] = {wx * (1.f - fy), wx * fy};

    float ch[12];
    #pragma unroll
    for (int c = 0; c < 12; c++) ch[c] = 0.f;
    float dd = 0.f;
    const int x = ix + dx;

    #pragma unroll
    for (int dy = 0; dy < 2; dy++) {
        float wc = wy[dy];
        size_t idx = (size_t)(x * 160 + (iy + dy)) * 160 + iz;
        if (VOX == 32) {
            const u32x4* e0 = (const u32x4*)(grid + idx * 8);
            const u32x4* e1 = (const u32x4*)(grid + (idx + 1) * 8);
            u32x4 a0 = e0[0], a1 = e0[1], b0 = e1[0], b1 = e1[1];
            unsigned int wz[6]  = {a0[0],a0[1],a0[2],a0[3],a1[0],a1[1]};
            unsigned int wz1[6] = {b0[0],b0[1],b0[2],b0[3],b1[0],b1[1]};
            #pragma unroll
            for (int j = 0; j < 6; j++) {
                ch[2*j]   += wc * (gz * blo(wz[j]) + fz * blo(wz1[j]));
                ch[2*j+1] += wc * (gz * bhi(wz[j]) + fz * bhi(wz1[j]));
            }
            dd += wc * (gz * __uint_as_float(a1[2]) + fz * __uint_as_float(b1[2]));
        } else {
            const u32x2* e = (const u32x2*)(grid + idx * 6);
            u32x2 a0 = e[0], a1 = e[1], a2 = e[2], a3 = e[3], a4 = e[4], a5 = e[5];
            unsigned int wz[6]  = {a0[0],a0[1],a1[0],a1[1],a2[0],a2[1]};
            unsigned int wz1[6] = {a3[0],a3[1],a4[0],a4[1],a5[0],a5[1]};
            #pragma unroll
            for (int j = 0; j < 6; j++) {
                ch[2*j]   += wc * (gz * blo(wz[j]) + fz * blo(wz1[j]));
                ch[2*j+1] += wc * (gz * bhi(wz[j]) + fz * bhi(wz1[j]));
            }
            const float* dr = dg + (size_t)(x * 160 + (iy + dy)) * 160 + iz;
            dd += wc * (gz * dr[0] + fz * dr[1]);
        }
    }

    #pragma unroll
    for (int c = 0; c < 12; c++) ch[c] += __shfl_xor(ch[c], 1);
    dd += __shfl_xor(dd, 1);

    if (dx == 0) {
        unsigned int w[8];
        w[0] = (unsigned int)f2b(ch[3]) | ((unsigned int)f2b(ch[4]) << 16);
        w[1] = (unsigned int)f2b(ch[5]) | ((unsigned int)f2b(ch[6]) << 16);
        w[2] = (unsigned int)f2b(ch[7]) | ((unsigned int)f2b(ch[8]) << 16);
        w[3] = (unsigned int)f2b(ch[9]) | ((unsigned int)f2b(ch[10]) << 16);
        w[4] = (unsigned int)f2b(ch[11]);
        w[5] = __float_as_uint(ch[0]);
        w[6] = __float_as_uint(ch[1]);
        w[7] = __float_as_uint(ch[2]);
        rec[(size_t)i*2]     = *(u32x4*)(w);
        rec[(size_t)i*2 + 1] = *(u32x4*)(w + 4);
    } else {
        float sp = softplusf(dd + ACT_SHIFT);
        float l  = -sp * DELTA;
        alog[i] = make_float2(1.f - expf(l), fmaxf(l, -15.9424285f));
    }
}

// ================= wave-per-ray scan =================
__global__ void k_scanw(const float2* __restrict__ alog, const int* __restrict__ starts,
                        float* __restrict__ wts, float* __restrict__ out, int R) {
    const int r = (blockIdx.x * blockDim.x + threadIdx.x) >> 6;
    const int lane = threadIdx.x & 63;
    if (r >= R) return;
    const int s = starts[r], e = starts[r + 1];
    float carry = 0.f;
    for (int i0 = s; i0 < e; i0 += 64) {
        int idx = i0 + lane;
        bool pr = idx < e;
        float a = 0.f, x = 0.f;
        if (pr) { float2 v = alog[idx]; a = v.x; x = v.y; }
        float incl = x;
        #pragma unroll
        for (int d = 1; d < 64; d <<= 1) {
            float tv = __shfl_up(incl, d);
            if (lane >= d) incl += tv;
        }
        if (pr) wts[idx] = a * expf(carry + (incl - x));
        carry += __shfl(incl, 63);
    }
    float ainv = expf(carry);
    if (lane == 0) { out[3*r] = ainv; out[3*r+1] = ainv; out[3*r+2] = ainv; }
}

// ================= MFMA MLP v6 (unchanged from round 11) =========================
// feat in hL[0,16KB) (rows 0-127 x 128B, XOR swz). h rows 64-127 live at [16KB,32KB):
// NO aliasing with feat. Store addr = sb[ntl][v] + row_block*4096 (XOR is mt-invariant).
__global__ __launch_bounds__(256, 3) void k_mlp_s(
    const u32x4* __restrict__ rec, const int* __restrict__ rid,
    const unsigned short* __restrict__ vemb, const float* __restrict__ wts,
    const unsigned short* __restrict__ Wt0, const float* __restrict__ b0,
    const unsigned short* __restrict__ Wt1, const float* __restrict__ b1,
    const unsigned short* __restrict__ Wt2, const float* __restrict__ b2,
    float* __restrict__ out, int M) {

    __shared__ char hL[128 * 256];     // 32 KB; feat aliased into first 16 KB
    __shared__ float diffL[128 * 3];
    __shared__ float wgtL[128];
    __shared__ int   ridL[128];

    const int t = threadIdx.x;
    const int base = blockIdx.x * 128;

    if (t < 128) {
        const int i = base + t;
        unsigned int fr[32];
        #pragma unroll
        for (int j = 19; j < 32; j++) fr[j] = 0u;
        float wpt = 0.f; int r = 0;
        float d0 = 0.f, d1 = 0.f, d2 = 0.f;
        if (i < M) {
            u32x4 r0 = rec[(size_t)i*2];
            u32x4 r1 = rec[(size_t)i*2 + 1];
            r = rid[i];
            wpt = wts[i];
            const unsigned int* vp = (const unsigned int*)(vemb + (size_t)r * 28);
            #pragma unroll
            for (int j = 0; j < 14; j++) fr[j] = vp[j];   // vemb (slot 27 pad=0)
            fr[14] = r0[0]; fr[15] = r0[1]; fr[16] = r0[2]; fr[17] = r0[3];
            fr[18] = r1[0] & 0xffffu;                      // (c11, 0)
            d0 = __uint_as_float(r1[1]); d1 = __uint_as_float(r1[2]); d2 = __uint_as_float(r1[3]);
        } else {
            #pragma unroll
            for (int j = 0; j < 19; j++) fr[j] = 0u;
        }
        diffL[t*3 + 0] = d0; diffL[t*3 + 1] = d1; diffL[t*3 + 2] = d2;
        wgtL[t] = wpt;
        ridL[t] = r;
        char* fp = hL + t * 128;
        unsigned int rs = (unsigned int)((t & 7) << 4);
        #pragma unroll
        for (int j = 0; j < 8; j++)
            *(u32x4*)(fp + ((16u*j) ^ rs)) = *(u32x4*)(fr + 4*j);
    }

    const int lane = t & 63;
    const int w = t >> 6;
    const int g = lane >> 4;
    const int ln = lane & 15;

    unsigned sb[2][4];
    #pragma unroll
    for (int ntl = 0; ntl < 2; ntl++) {
        const unsigned col2 = (unsigned)(((2*w + ntl)*16 + ln) * 2);
        #pragma unroll
        for (int v = 0; v < 4; v++) {
            const unsigned rsub = (unsigned)(4*g + v);
            sb[ntl][v] = ((rsub << 8) + col2) ^ ((rsub & 7u) << 4);
        }
    }

    short8 B1[2][2];
    float bias0[2];
    #pragma unroll
    for (int ntl = 0; ntl < 2; ntl++) {
        const int n0 = (2*w + ntl) * 16;
        const char* wb0 = (const char*)Wt0 + (n0 + ln) * 128 + 16*g;
        B1[ntl][0] = *(const short8*)(wb0);
        B1[ntl][1] = *(const short8*)(wb0 + 64);
        bias0[ntl] = b0[n0 + ln];
    }
    __syncthreads();   // feat staged

    // ---- L1 upper half (mt=4..7): compute + store immediately (no alias w/ feat) ----
    {
        f32x4 acc[4][2];
        #pragma unroll
        for (int mtl = 0; mtl < 4; mtl++) {
            const int arow = (4 + mtl)*16 + ln;
            const unsigned int aswz = (unsigned int)((arow & 7) << 4);
            const char* ab = hL + arow * 128;
            short8 a0 = *(const short8*)(ab + ((16u*g)        ^ aswz));
            short8 a1 = *(const short8*)(ab + ((64u + 16u*g)  ^ aswz));
            #pragma unroll
            for (int ntl = 0; ntl < 2; ntl++) {
                f32x4 a = {bias0[ntl], bias0[ntl], bias0[ntl], bias0[ntl]};
                a = __builtin_amdgcn_mfma_f32_16x16x32_bf16(a0, B1[ntl][0], a, 0, 0, 0);
                a = __builtin_amdgcn_mfma_f32_16x16x32_bf16(a1, B1[ntl][1], a, 0, 0, 0);
                acc[mtl][ntl] = a;
            }
        }
        #pragma unroll
        for (int mtl = 0; mtl < 4; mtl++) {
            #pragma unroll
            for (int ntl = 0; ntl < 2; ntl++) {
                #pragma unroll
                for (int v = 0; v < 4; v++) {
                    unsigned short hv = f2b_fast(fmaxf(acc[mtl][ntl][v], 0.f));
                    *(unsigned short*)(hL + sb[ntl][v] + 16384u + (unsigned)(mtl*4096)) = hv;
                }
            }
        }
    }

    // ---- L1 lower half (mt=0..3): compute into regs; store after barrier ----
    f32x4 accL[4][2];
    #pragma unroll
    for (int mtl = 0; mtl < 4; mtl++) {
        const int arow = mtl*16 + ln;
        const unsigned int aswz = (unsigned int)((arow & 7) << 4);
        const char* ab = hL + arow * 128;
        short8 a0 = *(const short8*)(ab + ((16u*g)        ^ aswz));
        short8 a1 = *(const short8*)(ab + ((64u + 16u*g)  ^ aswz));
        #pragma unroll
        for (int ntl = 0; ntl < 2; ntl++) {
            f32x4 a = {bias0[ntl], bias0[ntl], bias0[ntl], bias0[ntl]};
            a = __builtin_amdgcn_mfma_f32_16x16x32_bf16(a0, B1[ntl][0], a, 0, 0, 0);
            a = __builtin_amdgcn_mfma_f32_16x16x32_bf16(a1, B1[ntl][1], a, 0, 0, 0);
            accL[mtl][ntl] = a;
        }
    }
    short8 B2[2][4];
    float bias1[2];
    #pragma unroll
    for (int ntl = 0; ntl < 2; ntl++) {
        const int n0 = (2*w + ntl) * 16;
        const char* wb1 = (const char*)Wt1 + (n0 + ln) * 256 + 16*g;
        #pragma unroll
        for (int kk = 0; kk < 4; kk++)
            B2[ntl][kk] = *(const short8*)(wb1 + 64*kk);
        bias1[ntl] = b1[n0 + ln];
    }
    __syncthreads();   // all feat reads done -> safe to overwrite feat region
    #pragma unroll
    for (int mtl = 0; mtl < 4; mtl++) {
        #pragma unroll
        for (int ntl = 0; ntl < 2; ntl++) {
            #pragma unroll
            for (int v = 0; v < 4; v++) {
                unsigned short hv = f2b_fast(fmaxf(accL[mtl][ntl][v], 0.f));
                *(unsigned short*)(hL + sb[ntl][v] + (unsigned)(mtl*4096)) = hv;
            }
        }
    }
    __syncthreads();   // h1 fully visible

    // ---- L2 half A (mt=0..3) ----
    {
        f32x4 acc[4][2];
        #pragma unroll
        for (int mtl = 0; mtl < 4; mtl++) {
            const int arow = mtl*16 + ln;
            const unsigned int aswz = (unsigned int)((arow & 7) << 4);
            const char* ab = hL + arow * 256;
            short8 a0 = *(const short8*)(ab + ((16u*g)         ^ aswz));
            short8 a1 = *(const short8*)(ab + ((64u  + 16u*g)  ^ aswz));
            short8 a2 = *(const short8*)(ab + ((128u + 16u*g)  ^ aswz));
            short8 a3 = *(const short8*)(ab + ((192u + 16u*g)  ^ aswz));
            #pragma unroll
            for (int ntl = 0; ntl < 2; ntl++) {
                f32x4 a = {bias1[ntl], bias1[ntl], bias1[ntl], bias1[ntl]};
                a = __builtin_amdgcn_mfma_f32_16x16x32_bf16(a0, B2[ntl][0], a, 0, 0, 0);
                a = __builtin_amdgcn_mfma_f32_16x16x32_bf16(a1, B2[ntl][1], a, 0, 0, 0);
                a = __builtin_amdgcn_mfma_f32_16x16x32_bf16(a2, B2[ntl][2], a, 0, 0, 0);
                a = __builtin_amdgcn_mfma_f32_16x16x32_bf16(a3, B2[ntl][3], a, 0, 0, 0);
                acc[mtl][ntl] = a;
            }
        }
        __syncthreads();   // all reads of rows 0..63 done
        #pragma unroll
        for (int mtl = 0; mtl < 4; mtl++) {
            #pragma unroll
            for (int ntl = 0; ntl < 2; ntl++) {
                #pragma unroll
                for (int v = 0; v < 4; v++) {
                    unsigned short hv = f2b_fast(fmaxf(acc[mtl][ntl][v], 0.f));
                    *(unsigned short*)(hL + sb[ntl][v] + (unsigned)(mtl*4096)) = hv;
                }
            }
        }
    }

    // ---- L2 half B (mt=4..7) ----
    {
        f32x4 acc[4][2];
        #pragma unroll
        for (int mtl = 0; mtl < 4; mtl++) {
            const int arow = (4 + mtl)*16 + ln;
            const unsigned int aswz = (unsigned int)((arow & 7) << 4);
            const char* ab = hL + arow * 256;
            short8 a0 = *(const short8*)(ab + ((16u*g)         ^ aswz));
            short8 a1 = *(const short8*)(ab + ((64u  + 16u*g)  ^ aswz));
            short8 a2 = *(const short8*)(ab + ((128u + 16u*g)  ^ aswz));
            short8 a3 = *(const short8*)(ab + ((192u + 16u*g)  ^ aswz));
            #pragma unroll
            for (int ntl = 0; ntl < 2; ntl++) {
                f32x4 a = {bias1[ntl], bias1[ntl], bias1[ntl], bias1[ntl]};
                a = __builtin_amdgcn_mfma_f32_16x16x32_bf16(a0, B2[ntl][0], a, 0, 0, 0);
                a = __builtin_amdgcn_mfma_f32_16x16x32_bf16(a1, B2[ntl][1], a, 0, 0, 0);
                a = __builtin_amdgcn_mfma_f32_16x16x32_bf16(a2, B2[ntl][2], a, 0, 0, 0);
                a = __builtin_amdgcn_mfma_f32_16x16x32_bf16(a3, B2[ntl][3], a, 0, 0, 0);
                acc[mtl][ntl] = a;
            }
        }
        __syncthreads();   // all reads of rows 64..127 done
        #pragma unroll
        for (int mtl = 0; mtl < 4; mtl++) {
            #pragma unroll
            for (int ntl = 0; ntl < 2; ntl++) {
                #pragma unroll
                for (int v = 0; v < 4; v++) {
                    unsigned short hv = f2b_fast(fmaxf(acc[mtl][ntl][v], 0.f));
                    *(unsigned short*)(hL + sb[ntl][v] + 16384u + (unsigned)(mtl*4096)) = hv;
                }
            }
        }
    }

    short8 B3[4];
    {
        const char* wb2 = (const char*)Wt2 + ln * 256 + 16*g;
        #pragma unroll
        for (int kk = 0; kk < 4; kk++) B3[kk] = *(const short8*)(wb2 + 64*kk);
    }
    __syncthreads();   // h2 complete

    // ---- layer 3 (M-split: rows 32w..32w+31) + sigmoid + ray-merged atomics ----
    {
        const float b2c = (ln < 3) ? b2[ln] : 0.f;
        #pragma unroll
        for (int mi = 0; mi < 2; mi++) {
            const int m0 = 32*w + 16*mi;
            const int arow = m0 + ln;
            const unsigned int aswz = (unsigned int)((arow & 7) << 4);
            const char* ab = hL + arow * 256;
            short8 a0 = *(const short8*)(ab + ((16u*g)         ^ aswz));
            short8 a1 = *(const short8*)(ab + ((64u  + 16u*g)  ^ aswz));
            short8 a2 = *(const short8*)(ab + ((128u + 16u*g)  ^ aswz));
            short8 a3 = *(const short8*)(ab + ((192u + 16u*g)  ^ aswz));
            f32x4 acc = {0.f, 0.f, 0.f, 0.f};
            acc = __builtin_amdgcn_mfma_f32_16x16x32_bf16(a0, B3[0], acc, 0, 0, 0);
            acc = __builtin_amdgcn_mfma_f32_16x16x32_bf16(a1, B3[1], acc, 0, 0, 0);
            acc = __builtin_amdgcn_mfma_f32_16x16x32_bf16(a2, B3[2], acc, 0, 0, 0);
            acc = __builtin_amdgcn_mfma_f32_16x16x32_bf16(a3, B3[3], acc, 0, 0, 0);

            float val[4];
            #pragma unroll
            for (int v = 0; v < 4; v++) {
                int row = m0 + 4*g + v;
                float logit = acc[v] + b2c + diffL[row*3 + ln];
                val[v] = (ln < 3) ? wgtL[row] / (1.f + expf(-logit)) : 0.f;
            }
            int r0t = ridL[m0], r15t = ridL[m0 + 15];
            if (r0t == r15t) {
                float s = val[0] + val[1] + val[2] + val[3];
                s += __shfl_xor(s, 16);
                s += __shfl_xor(s, 32);
                if (g == 0 && ln < 3) atomicAdd(out + 3*r0t + ln, s);
            } else if (ln < 3) {
                int rr = ridL[m0 + 4*g];
                float run = val[0];
                #pragma unroll
                for (int v = 1; v < 4; v++) {
                    int rv = ridL[m0 + 4*g + v];
                    if (rv == rr) run += val[v];
                    else { atomicAdd(out + 3*rr + ln, run); run = val[v]; rr = rv; }
                }
                atomicAdd(out + 3*rr + ln, run);
            }
        }
    }
}

// ================= legacy fused MLP (ultra fallback, 24B grid) =================
__global__ __launch_bounds__(256) void k_mlp_fused(
    const unsigned short* __restrict__ k0b, const float* __restrict__ xyz,
    const int* __restrict__ rid, const unsigned short* __restrict__ vemb,
    const float* __restrict__ wts,
    const unsigned short* __restrict__ Wt0, const float* __restrict__ b0,
    const unsigned short* __restrict__ Wt1, const float* __restrict__ b1,
    const unsigned short* __restrict__ Wt2, const float* __restrict__ b2,
    float* __restrict__ out, int M) {

    __shared__ char featL[128 * 128];
    __shared__ char hL[128 * 256];
    __shared__ float diffL[128 * 3];
    __shared__ float wgtL[128];
    __shared__ int   ridL[128];

    const int t = threadIdx.x;
    const int base = blockIdx.x * 128;
    const int p = t >> 1;
    const int dx = t & 1;
    const int i = base + p;

    float ch[12];
    #pragma unroll
    for (int c = 0; c < 12; c++) ch[c] = 0.f;

    if (i < M) {
        int ix, iy, iz; float fx, fy, fz;
        trisetup(xyz[3*i], xyz[3*i+1], xyz[3*i+2], ix, iy, iz, fx, fy, fz);
        float gz = 1.f - fz;
        float wx = dx ? fx : (1.f - fx);
        float wy0 = wx * (1.f - fy), wy1 = wx * fy;
        #pragma unroll
        for (int dy = 0; dy < 2; dy++) {
            float w2 = dy ? wy1 : wy0;
            size_t vox = (size_t)((ix + dx) * 160 + (iy + dy)) * 160 + iz;
            const char* pv = (const char*)k0b + vox * 24;
            u32x2 a0 = *(const u32x2*)(pv);
            u32x2 a1 = *(const u32x2*)(pv + 8);
            u32x2 a2 = *(const u32x2*)(pv + 16);
            u32x2 a3 = *(const u32x2*)(pv + 24);
            u32x2 a4 = *(const u32x2*)(pv + 32);
            u32x2 a5 = *(const u32x2*)(pv + 40);
            unsigned int u0[6] = {a0[0],a0[1],a1[0],a1[1],a2[0],a2[1]};
            unsigned int u1[6] = {a3[0],a3[1],a4[0],a4[1],a5[0],a5[1]};
            #pragma unroll
            for (int j = 0; j < 6; j++) {
                ch[2*j]   += w2 * (gz * blo(u0[j]) + fz * blo(u1[j]));
                ch[2*j+1] += w2 * (gz * bhi(u0[j]) + fz * bhi(u1[j]));
            }
        }
    }
    #pragma unroll
    for (int c = 0; c < 12; c++) ch[c] += __shfl_xor(ch[c], 1);

    if (dx == 0) {
        unsigned int fr[32];
        #pragma unroll
        for (int j = 19; j < 32; j++) fr[j] = 0u;
        float wpt = 0.f; int r = 0;
        if (i < M) {
            r = rid[i];
            wpt = wts[i];
            const unsigned int* vp = (const unsigned int*)(vemb + (size_t)r * 28);
            #pragma unroll
            for (int j = 0; j < 14; j++) fr[j] = vp[j];
            fr[14] = (unsigned int)f2b(ch[3]) | ((unsigned int)f2b(ch[4]) << 16);
            fr[15] = (unsigned int)f2b(ch[5]) | ((unsigned int)f2b(ch[6]) << 16);
            fr[16] = (unsigned int)f2b(ch[7]) | ((unsigned int)f2b(ch[8]) << 16);
            fr[17] = (unsigned int)f2b(ch[9]) | ((unsigned int)f2b(ch[10]) << 16);
            fr[18] = (unsigned int)f2b(ch[11]);
        } else {
            #pragma unroll
            for (int j = 0; j < 19; j++) fr[j] = 0u;
        }
        diffL[p*3 + 0] = ch[0];
        diffL[p*3 + 1] = ch[1];
        diffL[p*3 + 2] = ch[2];
        wgtL[p] = wpt;
        ridL[p] = r;
        char* fp = featL + p * 128;
        unsigned int rs = (unsigned int)((p & 7) << 4);
        #pragma unroll
        for (int j = 0; j < 8; j++)
            *(u32x4*)(fp + ((16u*j) ^ rs)) = *(u32x4*)(fr + 4*j);
    }
    __syncthreads();

    const int lane = t & 63;
    const int w = t >> 6;
    const int g = lane >> 4;
    const int ln = lane & 15;

    #pragma unroll
    for (int mi = 0; mi < 2; mi++) {
        const int m0 = 32*w + 16*mi;
        const int arow = m0 + ln;
        const unsigned int aswz = (unsigned int)((arow & 7) << 4);
        const char* ab = featL + arow * 128;
        short8 a0 = *(const short8*)(ab + ((16u*g)        ^ aswz));
        short8 a1 = *(const short8*)(ab + ((64u + 16u*g)  ^ aswz));
        #pragma unroll
        for (int nt = 0; nt < 8; nt++) {
            const int n0 = 16 * nt;
            float bias = b0[n0 + ln];
            f32x4 acc = {bias, bias, bias, bias};
            const char* wb = (const char*)Wt0 + (n0 + ln) * 128;
            acc = __builtin_amdgcn_mfma_f32_16x16x32_bf16(a0, *(const short8*)(wb + 16*g),      acc, 0, 0, 0);
            acc = __builtin_amdgcn_mfma_f32_16x16x32_bf16(a1, *(const short8*)(wb + 64 + 16*g), acc, 0, 0, 0);
            #pragma unroll
            for (int v = 0; v < 4; v++) {
                int row = m0 + 4*g + v;
                unsigned short hv = f2b_fast(fmaxf(acc[v], 0.f));
                *(unsigned short*)(hL + (((unsigned)(row*256 + (n0+ln)*2)) ^ ((unsigned)((row & 7) << 4)))) = hv;
            }
        }
    }

    #pragma unroll
    for (int mi = 0; mi < 2; mi++) {
        const int m0 = 32*w + 16*mi;
        const int arow = m0 + ln;
        const unsigned int aswz = (unsigned int)((arow & 7) << 4);
        const char* ab = hL + arow * 256;
        short8 a0 = *(const short8*)(ab + ((16u*g)         ^ aswz));
        short8 a1 = *(const short8*)(ab + ((64u  + 16u*g)  ^ aswz));
        short8 a2 = *(const short8*)(ab + ((128u + 16u*g)  ^ aswz));
        short8 a3 = *(const short8*)(ab + ((192u + 16u*g)  ^ aswz));
        #pragma unroll
        for (int nt = 0; nt < 8; nt++) {
            const int n0 = 16 * nt;
            float bias = b1[n0 + ln];
            f32x4 acc = {bias, bias, bias, bias};
            const char* wb = (const char*)Wt1 + (n0 + ln) * 256;
            acc = __builtin_amdgcn_mfma_f32_16x16x32_bf16(a0, *(const short8*)(wb + 16*g),       acc, 0, 0, 0);
            acc = __builtin_amdgcn_mfma_f32_16x16x32_bf16(a1, *(const short8*)(wb + 64 + 16*g),  acc, 0, 0, 0);
            acc = __builtin_amdgcn_mfma_f32_16x16x32_bf16(a2, *(const short8*)(wb + 128 + 16*g), acc, 0, 0, 0);
            acc = __builtin_amdgcn_mfma_f32_16x16x32_bf16(a3, *(const short8*)(wb + 192 + 16*g), acc, 0, 0, 0);
            #pragma unroll
            for (int v = 0; v < 4; v++) {
                int row = m0 + 4*g + v;
                unsigned short hv = f2b_fast(fmaxf(acc[v], 0.f));
                *(unsigned short*)(hL + (((unsigned)(row*256 + (n0+ln)*2)) ^ ((unsigned)((row & 7) << 4)))) = hv;
            }
        }
    }

    const float b2c = (ln < 3) ? b2[ln] : 0.f;
    #pragma unroll
    for (int mi = 0; mi < 2; mi++) {
        const int m0 = 32*w + 16*mi;
        const int arow = m0 + ln;
        const unsigned int aswz = (unsigned int)((arow & 7) << 4);
        const char* ab = hL + arow * 256;
        short8 a0 = *(const short8*)(ab + ((16u*g)         ^ aswz));
        short8 a1 = *(const short8*)(ab + ((64u  + 16u*g)  ^ aswz));
        short8 a2 = *(const short8*)(ab + ((128u + 16u*g)  ^ aswz));
        short8 a3 = *(const short8*)(ab + ((192u + 16u*g)  ^ aswz));
        f32x4 acc = {0.f, 0.f, 0.f, 0.f};
        const char* wb = (const char*)Wt2 + ln * 256;
        acc = __builtin_amdgcn_mfma_f32_16x16x32_bf16(a0, *(const short8*)(wb + 16*g),       acc, 0, 0, 0);
        acc = __builtin_amdgcn_mfma_f32_16x16x32_bf16(a1, *(const short8*)(wb + 64 + 16*g),  acc, 0, 0, 0);
        acc = __builtin_amdgcn_mfma_f32_16x16x32_bf16(a2, *(const short8*)(wb + 128 + 16*g), acc, 0, 0, 0);
        acc = __builtin_amdgcn_mfma_f32_16x16x32_bf16(a3, *(const short8*)(wb + 192 + 16*g), acc, 0, 0, 0);

        float val[4];
        #pragma unroll
        for (int v = 0; v < 4; v++) {
            int row = m0 + 4*g + v;
            float logit = acc[v] + b2c + diffL[row*3 + ln];
            val[v] = (ln < 3) ? wgtL[row] / (1.f + expf(-logit)) : 0.f;
        }
        int r0t = ridL[m0], r15t = ridL[m0 + 15];
        if (r0t == r15t) {
            float s = val[0] + val[1] + val[2] + val[3];
            s += __shfl_xor(s, 16);
            s += __shfl_xor(s, 32);
            if (g == 0 && ln < 3) atomicAdd(out + 3*r0t + ln, s);
        } else if (ln < 3) {
            int rr = ridL[m0 + 4*g];
            float run = val[0];
            #pragma unroll
            for (int v = 1; v < 4; v++) {
                int rv = ridL[m0 + 4*g + v];
                if (rv == rr) run += val[v];
                else { atomicAdd(out + 3*rr + ln, run); run = val[v]; rr = rv; }
            }
            atomicAdd(out + 3*rr + ln, run);
        }
    }
}

extern "C" void kernel_launch(void* const* d_in, const int* in_sizes, int n_in,
                              void* d_out, int out_size, void* d_ws, size_t ws_size,
                              hipStream_t stream) {
    const float* dg  = (const float*)d_in[0];
    const float* k0  = (const float*)d_in[1];
    const float* xyz = (const float*)d_in[2];
    const float* vd  = (const float*)d_in[3];
    const float* W0  = (const float*)d_in[4];
    const float* b0  = (const float*)d_in[5];
    const float* W1  = (const float*)d_in[6];
    const float* b1  = (const float*)d_in[7];
    const float* W2  = (const float*)d_in[8];
    const float* b2  = (const float*)d_in[9];
    const int*   rid = (const int*)d_in[10];
    float* out = (float*)d_out;

    const int M = in_sizes[2] / 3;
    const int R = in_sizes[3] / 3;

    const size_t wtb    = (size_t)(128*64 + 128*128 + 16*128) * 2;
    const size_t vembsz = (size_t)R * 28 * 2;
    const size_t alogsz = (size_t)M * 8;
    const size_t wtssz  = (size_t)M * 4;
    const size_t stsz   = (size_t)(R + 1) * 4;
    const size_t recsz  = (size_t)M * 32;
    const size_t fixed  = wtb + vembsz + alogsz + wtssz + stsz + 1024;

    const size_t need32 = (size_t)NVOX * 32 + fixed + recsz;
    const size_t need24 = (size_t)NVOX * 24 + fixed + recsz;

    // Prefer VOX32: 131 MB grid is Infinity-Cache-resident (VOX64's 262 MB is not).
    int tier = (ws_size >= need32) ? 32 : (ws_size >= need24) ? 24 : 0;
    const size_t gridb = (tier == 32) ? (size_t)NVOX*32 : (size_t)NVOX*24;

    char* w = (char*)d_ws;
    unsigned int*   gridp = (unsigned int*)w;   w += gridb;
    unsigned short* Wt0   = (unsigned short*)w; w += 128*64*2;
    unsigned short* Wt1   = (unsigned short*)w; w += 128*128*2;
    unsigned short* Wt2   = (unsigned short*)w; w += 16*128*2;
    unsigned short* vembb = (unsigned short*)w; w += vembsz;
    float2* alog  = (float2*)w;  w += alogsz;
    float*  wts   = (float*)w;   w += wtssz;
    int*    starts= (int*)w;     w += stsz;
    w = (char*)(((size_t)w + 255) & ~(size_t)255);
    u32x4*  rec   = (u32x4*)w;

    const int gb = (NVOX + 255) / 256;
    k_wprep <<<dim3(64), dim3(256), 0, stream>>>(W0, W1, W2, Wt0, Wt1, Wt2);
    k_starts<<<dim3((R + 256) / 256), dim3(256), 0, stream>>>(rid, starts, M, R);
    k_vdemb <<<dim3((R + 255) / 256), dim3(256), 0, stream>>>(vd, vembb, R);

    if (tier > 0) {
        if (tier == 32) k_t32<<<dim3(gb), dim3(256), 0, stream>>>(k0, dg, gridp);
        else            k_t24<<<dim3(gb), dim3(256), 0, stream>>>(k0, gridp);

        const int gblocks = (2 * M + 255) / 256;
        if (tier == 32)
            k_gather<32><<<dim3(gblocks), dim3(256), 0, stream>>>(gridp, dg, xyz, rec, alog, M);
        else
            k_gather<24><<<dim3(gblocks), dim3(256), 0, stream>>>(gridp, dg, xyz, rec, alog, M);

        k_scanw<<<dim3(((size_t)R * 64 + 255) / 256), dim3(256), 0, stream>>>(alog, starts, wts, out, R);
        k_mlp_s<<<dim3((M + 127) / 128), dim3(256), 0, stream>>>(rec, rid, vembb, wts,
                                                                 Wt0, b0, Wt1, b1, Wt2, b2, out, M);
    } else {
        k_t24    <<<dim3(gb), dim3(256), 0, stream>>>(k0, gridp);
        k_densityC<<<dim3((M + 255) / 256), dim3(256), 0, stream>>>(dg, xyz, alog, M);
        k_scanw  <<<dim3(((size_t)R * 64 + 255) / 256), dim3(256), 0, stream>>>(alog, starts, wts, out, R);
        k_mlp_fused<<<dim3((M + 127) / 128), dim3(256), 0, stream>>>((const unsigned short*)gridp, xyz, rid, vembb, wts,
                                                                     Wt0, b0, Wt1, b1, Wt2, b2, out, M);
    }
}